// Round 1
// baseline (4773.744 us; speedup 1.0000x reference)
//
#include <hip/hip_runtime.h>
#include <math.h>

#define SCALE_F 0.0721687836487032f  // 192^-0.5

// ---------------------------------------------------------------------------
// GEMM: C[M,N] = A[M,K] @ W[N,K]^T   (fp32, 64x64 tile, BK=32, 256 thr)
// M covered by gridDim.y*64, N by gridDim.x*64. lda = A row stride.
// All dims here are multiples of the tile sizes (checked host-side shapes).
// ---------------------------------------------------------------------------
__global__ __launch_bounds__(256) void gemm_at(
    const float* __restrict__ A, int lda,
    const float* __restrict__ W,
    float* __restrict__ C, int N, int K)
{
  // As/Ws stored [k][m], stride 68 floats: 68*4=272B %16==0 -> b128-aligned reads
  __shared__ __align__(16) float As[32][68];
  __shared__ __align__(16) float Ws[32][68];
  const int tid = threadIdx.x;
  const int bm = blockIdx.y * 64;
  const int bn = blockIdx.x * 64;
  const int lr = tid >> 2;          // 0..63 loader row
  const int lc = (tid & 3) * 8;     // 0,8,16,24 loader k-offset
  const int ty = tid >> 4;          // 0..15 -> C rows ty*4..+3
  const int tx = tid & 15;          // 0..15 -> C cols tx*4..+3

  float acc[4][4] = {};

  for (int k0 = 0; k0 < K; k0 += 32) {
    const float* ap = A + (size_t)(bm + lr) * lda + k0 + lc;
    const float* wp = W + (size_t)(bn + lr) * K   + k0 + lc;
    float4 a0 = *(const float4*)ap;
    float4 a1 = *(const float4*)(ap + 4);
    float4 w0 = *(const float4*)wp;
    float4 w1 = *(const float4*)(wp + 4);
    As[lc+0][lr] = a0.x; As[lc+1][lr] = a0.y; As[lc+2][lr] = a0.z; As[lc+3][lr] = a0.w;
    As[lc+4][lr] = a1.x; As[lc+5][lr] = a1.y; As[lc+6][lr] = a1.z; As[lc+7][lr] = a1.w;
    Ws[lc+0][lr] = w0.x; Ws[lc+1][lr] = w0.y; Ws[lc+2][lr] = w0.z; Ws[lc+3][lr] = w0.w;
    Ws[lc+4][lr] = w1.x; Ws[lc+5][lr] = w1.y; Ws[lc+6][lr] = w1.z; Ws[lc+7][lr] = w1.w;
    __syncthreads();
    #pragma unroll
    for (int kk = 0; kk < 32; ++kk) {
      float4 av = *(const float4*)&As[kk][ty * 4];
      float4 wv = *(const float4*)&Ws[kk][tx * 4];
      float a[4] = {av.x, av.y, av.z, av.w};
      float w[4] = {wv.x, wv.y, wv.z, wv.w};
      #pragma unroll
      for (int i = 0; i < 4; ++i)
        #pragma unroll
        for (int j = 0; j < 4; ++j)
          acc[i][j] += a[i] * w[j];
    }
    __syncthreads();
  }

  #pragma unroll
  for (int i = 0; i < 4; ++i) {
    float4 v = make_float4(acc[i][0], acc[i][1], acc[i][2], acc[i][3]);
    *(float4*)(C + (size_t)(bm + ty * 4 + i) * N + bn + tx * 4) = v;
  }
}

// ---------------------------------------------------------------------------
// RMSNorm rows in place: x *= rsqrt(mean(x^2)+eps)*gamma, first C cols of each
// stride-row. One block per row.
// ---------------------------------------------------------------------------
__global__ __launch_bounds__(256) void rmsnorm_rows(
    float* __restrict__ X, const float* __restrict__ gamma, int C, int stride)
{
  float* x = X + (size_t)blockIdx.x * stride;
  const int tid = threadIdx.x;
  float ss = 0.f;
  for (int c = tid; c < C; c += 256) { float v = x[c]; ss += v * v; }
  #pragma unroll
  for (int off = 32; off > 0; off >>= 1) ss += __shfl_down(ss, off, 64);
  __shared__ float red[4];
  if ((tid & 63) == 0) red[tid >> 6] = ss;
  __syncthreads();
  float tot = red[0] + red[1] + red[2] + red[3];
  float scale = rsqrtf(tot / (float)C + 1e-6f);
  for (int c = tid; c < C; c += 256) x[c] = x[c] * scale * gamma[c];
}

// ---------------------------------------------------------------------------
// RoPE on q: q is (M=4096, NH=16, 192); rotate last 64 dims of each head.
// cos/sin are (M, 64). One thread per (m,h,pair i<32).
// ---------------------------------------------------------------------------
__global__ __launch_bounds__(256) void rope_q(
    float* __restrict__ q, const float* __restrict__ cosb, const float* __restrict__ sinb)
{
  int idx = blockIdx.x * 256 + threadIdx.x;   // M*NH*32 total
  int i = idx & 31;
  int h = (idx >> 5) & 15;
  int m = idx >> 9;
  float* x = q + (size_t)m * 3072 + h * 192 + 128;
  const float* cb = cosb + (size_t)m * 64;
  const float* sb = sinb + (size_t)m * 64;
  float x1 = x[i], x2 = x[i + 32];
  x[i]      = x1 * cb[i]      - x2 * sb[i];
  x[i + 32] = x2 * cb[i + 32] + x1 * sb[i + 32];
}

// RoPE on shared k_rope: kv is (M, 576), cols 512..575. One thread per (m, i<32).
__global__ __launch_bounds__(256) void rope_k(
    float* __restrict__ kvb, const float* __restrict__ cosb, const float* __restrict__ sinb)
{
  int idx = blockIdx.x * 256 + threadIdx.x;   // M*32 total
  int i = idx & 31;
  int m = idx >> 5;
  float* x = kvb + (size_t)m * 576 + 512;
  const float* cb = cosb + (size_t)m * 64;
  const float* sb = sinb + (size_t)m * 64;
  float x1 = x[i], x2 = x[i + 32];
  x[i]      = x1 * cb[i]      - x2 * sb[i];
  x[i + 32] = x2 * cb[i + 32] + x1 * sb[i + 32];
}

// ---------------------------------------------------------------------------
// Causal flash attention, fp32. Block = (q-tile of 32, head, batch), 256 thr.
// q:   (M, 16, 192)  (nope 0..127, roped rope 128..191), pre-scaled here
// kvx: (M, 16, 256)  (k_nope 0..127, v 128..255)
// kvb: (M, 576)      (roped shared k_rope at 512..575)
// attn:(M, 16, 128)
// ---------------------------------------------------------------------------
__global__ __launch_bounds__(256) void flash_attn(
    const float* __restrict__ qb, const float* __restrict__ kvx,
    const float* __restrict__ kvb, float* __restrict__ attn)
{
  const int QSTR = 204;   // 204*4=816B %16==0, and %32 banks pattern conflict-free
  __shared__ __align__(16) float Qs[32 * 204];
  __shared__ __align__(16) float Ks[32 * 204];
  __shared__ __align__(16) float Vs[32 * 128];
  __shared__ __align__(16) float Ps[32 * 33];
  __shared__ float aS[32], lS[32];

  const int qt = blockIdx.x, h = blockIdx.y, b = blockIdx.z;
  const int tid = threadIdx.x;
  const int qg0 = qt * 32;
  const size_t mb = (size_t)b * 2048;

  // load + pre-scale Q tile (32 x 192)
  for (int i = tid; i < 32 * 192; i += 256) {
    int r = i / 192, c = i - r * 192;
    Qs[r * QSTR + c] = qb[((mb + qg0 + r) * 16 + h) * 192 + c] * SCALE_F;
  }

  float m_i = -INFINITY, l_i = 0.f;           // live in threads tid<32
  float4 Ov[4];
  #pragma unroll
  for (int g = 0; g < 4; ++g) Ov[g] = make_float4(0.f, 0.f, 0.f, 0.f);

  const int orow = tid >> 3;       // 0..31: O row
  const int olane = tid & 7;       // float4 col group

  for (int kt = 0; kt <= qt; ++kt) {
    const int kg0 = kt * 32;
    for (int i = tid; i < 32 * 192; i += 256) {
      int r = i / 192, c = i - r * 192;
      size_t m2 = mb + kg0 + r;
      Ks[r * QSTR + c] = (c < 128) ? kvx[(m2 * 16 + h) * 256 + c]
                                   : kvb[m2 * 576 + 512 + (c - 128)];
    }
    for (int i = tid; i < 32 * 128; i += 256) {
      int r = i >> 7, c = i & 127;
      Vs[i] = kvx[((mb + kg0 + r) * 16 + h) * 256 + 128 + c];
    }
    __syncthreads();

    // scores: thread -> row r = tid>>3, cols c0..c0+3
    {
      const int r = tid >> 3, c0 = (tid & 7) * 4;
      const float* qr = &Qs[r * QSTR];
      const float* kp0 = &Ks[(c0 + 0) * QSTR];
      const float* kp1 = &Ks[(c0 + 1) * QSTR];
      const float* kp2 = &Ks[(c0 + 2) * QSTR];
      const float* kp3 = &Ks[(c0 + 3) * QSTR];
      float s0 = 0.f, s1 = 0.f, s2 = 0.f, s3 = 0.f;
      #pragma unroll 8
      for (int d = 0; d < 192; d += 4) {
        float4 qv = *(const float4*)(qr + d);
        float4 k0 = *(const float4*)(kp0 + d);
        float4 k1 = *(const float4*)(kp1 + d);
        float4 k2 = *(const float4*)(kp2 + d);
        float4 k3 = *(const float4*)(kp3 + d);
        s0 += qv.x * k0.x + qv.y * k0.y + qv.z * k0.z + qv.w * k0.w;
        s1 += qv.x * k1.x + qv.y * k1.y + qv.z * k1.z + qv.w * k1.w;
        s2 += qv.x * k2.x + qv.y * k2.y + qv.z * k2.z + qv.w * k2.w;
        s3 += qv.x * k3.x + qv.y * k3.y + qv.z * k3.z + qv.w * k3.w;
      }
      const bool diag = (kt == qt);
      Ps[r * 33 + c0 + 0] = (diag && (c0 + 0 > r)) ? -INFINITY : s0;
      Ps[r * 33 + c0 + 1] = (diag && (c0 + 1 > r)) ? -INFINITY : s1;
      Ps[r * 33 + c0 + 2] = (diag && (c0 + 2 > r)) ? -INFINITY : s2;
      Ps[r * 33 + c0 + 3] = (diag && (c0 + 3 > r)) ? -INFINITY : s3;
    }
    __syncthreads();

    // online softmax per row (threads 0..31)
    if (tid < 32) {
      float mx = -INFINITY;
      #pragma unroll
      for (int c = 0; c < 32; ++c) mx = fmaxf(mx, Ps[tid * 33 + c]);
      float mnew = fmaxf(m_i, mx);
      float alpha = __expf(m_i - mnew);
      float rs = 0.f;
      #pragma unroll
      for (int c = 0; c < 32; ++c) {
        float p = __expf(Ps[tid * 33 + c] - mnew);
        Ps[tid * 33 + c] = p;
        rs += p;
      }
      l_i = l_i * alpha + rs;
      m_i = mnew;
      aS[tid] = alpha;
    }
    __syncthreads();

    // O update
    {
      float alpha = aS[orow];
      #pragma unroll
      for (int g = 0; g < 4; ++g) {
        Ov[g].x *= alpha; Ov[g].y *= alpha; Ov[g].z *= alpha; Ov[g].w *= alpha;
      }
      const float* pr = &Ps[orow * 33];
      #pragma unroll 8
      for (int k = 0; k < 32; ++k) {
        float p = pr[k];
        const float4* vr = (const float4*)&Vs[k * 128];
        #pragma unroll
        for (int g = 0; g < 4; ++g) {
          float4 vv = vr[olane + 8 * g];
          Ov[g].x += p * vv.x; Ov[g].y += p * vv.y;
          Ov[g].z += p * vv.z; Ov[g].w += p * vv.w;
        }
      }
    }
    __syncthreads();
  }

  if (tid < 32) lS[tid] = l_i;
  __syncthreads();
  float inv_l = 1.f / lS[orow];
  float* op = attn + ((mb + qg0 + orow) * 16 + h) * 128;
  #pragma unroll
  for (int g = 0; g < 4; ++g) {
    float4 v = Ov[g];
    v.x *= inv_l; v.y *= inv_l; v.z *= inv_l; v.w *= inv_l;
    *(float4*)(op + olane * 4 + 32 * g) = v;
  }
}

// ---------------------------------------------------------------------------
extern "C" void kernel_launch(void* const* d_in, const int* in_sizes, int n_in,
                              void* d_out, int out_size, void* d_ws, size_t ws_size,
                              hipStream_t stream)
{
  const float* hidden   = (const float*)d_in[0];
  const float* cosb     = (const float*)d_in[1];
  const float* sinb     = (const float*)d_in[2];
  const float* Wq_down  = (const float*)d_in[3];
  const float* q_gamma  = (const float*)d_in[4];
  const float* Wq_up    = (const float*)d_in[5];
  const float* Wkv_down = (const float*)d_in[6];
  const float* kv_gamma = (const float*)d_in[7];
  const float* Wkv_up   = (const float*)d_in[8];
  const float* Wo       = (const float*)d_in[9];
  float* out = (float*)d_out;

  float* p = (float*)d_ws;
  float* q_lat = p;  p += (size_t)4096 * 1536;   // 6.29M
  float* kvbuf = p;  p += (size_t)4096 * 576;    // 2.36M
  float* qbuf  = p;  p += (size_t)4096 * 3072;   // 12.58M
  float* kvx   = p;  p += (size_t)4096 * 4096;   // 16.78M
  float* attn  = p;  p += (size_t)4096 * 2048;   // 8.39M  (total ~178 MB)

  dim3 blk(256);

  // 1) q_lat = hidden @ Wq_down^T          (4096,1536) K=2048
  gemm_at<<<dim3(1536 / 64, 4096 / 64), blk, 0, stream>>>(hidden, 2048, Wq_down, q_lat, 1536, 2048);
  // 2) kv = hidden @ Wkv_down^T            (4096,576)  K=2048
  gemm_at<<<dim3(576 / 64, 4096 / 64), blk, 0, stream>>>(hidden, 2048, Wkv_down, kvbuf, 576, 2048);
  // 3) rmsnorm(q_lat)
  rmsnorm_rows<<<4096, blk, 0, stream>>>(q_lat, q_gamma, 1536, 1536);
  // 4) rmsnorm(c_kv = kv[:, :512])
  rmsnorm_rows<<<4096, blk, 0, stream>>>(kvbuf, kv_gamma, 512, 576);
  // 5) rope on shared k_rope (kv[:, 512:576])
  rope_k<<<(4096 * 32) / 256, blk, 0, stream>>>(kvbuf, cosb, sinb);
  // 6) q = q_lat @ Wq_up^T                 (4096,3072) K=1536
  gemm_at<<<dim3(3072 / 64, 4096 / 64), blk, 0, stream>>>(q_lat, 1536, Wq_up, qbuf, 3072, 1536);
  // 7) rope on q (last 64 dims per head)
  rope_q<<<(4096 * 16 * 32) / 256, blk, 0, stream>>>(qbuf, cosb, sinb);
  // 8) kvx = c_kv @ Wkv_up^T               (4096,4096) K=512
  gemm_at<<<dim3(4096 / 64, 4096 / 64), blk, 0, stream>>>(kvbuf, 576, Wkv_up, kvx, 4096, 512);
  // 9) flash attention -> attn (4096, 16, 128)
  flash_attn<<<dim3(2048 / 32, 16, 2), blk, 0, stream>>>(qbuf, kvx, kvbuf, attn);
  // 10) out = attn @ Wo^T                  (4096,2048) K=2048
  gemm_at<<<dim3(2048 / 64, 4096 / 64), blk, 0, stream>>>(attn, 2048, Wo, out, 2048, 2048);
}

// Round 2
// 2249.603 us; speedup vs baseline: 2.1220x; 2.1220x over previous
//
#include <hip/hip_runtime.h>
#include <math.h>

#define SCALE_F 0.0721687836487032f  // 192^-0.5
#define NEG_BIG -3.0e38f

typedef __attribute__((ext_vector_type(8))) short bf16x8;
typedef __attribute__((ext_vector_type(4))) float f32x4;

static __device__ __forceinline__ short f2bf(float f) {
  unsigned u = __float_as_uint(f);
  u += 0x7fffu + ((u >> 16) & 1u);   // RNE
  return (short)(u >> 16);
}

// ---------------------------------------------------------------------------
// GEMM: C[M,N] = A[M,K] @ W[N,K]^T   (fp32, 64x64 tile, BK=32, 256 thr)
// ---------------------------------------------------------------------------
__global__ __launch_bounds__(256) void gemm_at(
    const float* __restrict__ A, int lda,
    const float* __restrict__ W,
    float* __restrict__ C, int N, int K)
{
  __shared__ __align__(16) float As[32][68];
  __shared__ __align__(16) float Ws[32][68];
  const int tid = threadIdx.x;
  const int bm = blockIdx.y * 64;
  const int bn = blockIdx.x * 64;
  const int lr = tid >> 2;
  const int lc = (tid & 3) * 8;
  const int ty = tid >> 4;
  const int tx = tid & 15;

  float acc[4][4] = {};

  for (int k0 = 0; k0 < K; k0 += 32) {
    const float* ap = A + (size_t)(bm + lr) * lda + k0 + lc;
    const float* wp = W + (size_t)(bn + lr) * K   + k0 + lc;
    float4 a0 = *(const float4*)ap;
    float4 a1 = *(const float4*)(ap + 4);
    float4 w0 = *(const float4*)wp;
    float4 w1 = *(const float4*)(wp + 4);
    As[lc+0][lr] = a0.x; As[lc+1][lr] = a0.y; As[lc+2][lr] = a0.z; As[lc+3][lr] = a0.w;
    As[lc+4][lr] = a1.x; As[lc+5][lr] = a1.y; As[lc+6][lr] = a1.z; As[lc+7][lr] = a1.w;
    Ws[lc+0][lr] = w0.x; Ws[lc+1][lr] = w0.y; Ws[lc+2][lr] = w0.z; Ws[lc+3][lr] = w0.w;
    Ws[lc+4][lr] = w1.x; Ws[lc+5][lr] = w1.y; Ws[lc+6][lr] = w1.z; Ws[lc+7][lr] = w1.w;
    __syncthreads();
    #pragma unroll
    for (int kk = 0; kk < 32; ++kk) {
      float4 av = *(const float4*)&As[kk][ty * 4];
      float4 wv = *(const float4*)&Ws[kk][tx * 4];
      float a[4] = {av.x, av.y, av.z, av.w};
      float w[4] = {wv.x, wv.y, wv.z, wv.w};
      #pragma unroll
      for (int i = 0; i < 4; ++i)
        #pragma unroll
        for (int j = 0; j < 4; ++j)
          acc[i][j] += a[i] * w[j];
    }
    __syncthreads();
  }

  #pragma unroll
  for (int i = 0; i < 4; ++i) {
    float4 v = make_float4(acc[i][0], acc[i][1], acc[i][2], acc[i][3]);
    *(float4*)(C + (size_t)(bm + ty * 4 + i) * N + bn + tx * 4) = v;
  }
}

// ---------------------------------------------------------------------------
__global__ __launch_bounds__(256) void rmsnorm_rows(
    float* __restrict__ X, const float* __restrict__ gamma, int C, int stride)
{
  float* x = X + (size_t)blockIdx.x * stride;
  const int tid = threadIdx.x;
  float ss = 0.f;
  for (int c = tid; c < C; c += 256) { float v = x[c]; ss += v * v; }
  #pragma unroll
  for (int off = 32; off > 0; off >>= 1) ss += __shfl_down(ss, off, 64);
  __shared__ float red[4];
  if ((tid & 63) == 0) red[tid >> 6] = ss;
  __syncthreads();
  float tot = red[0] + red[1] + red[2] + red[3];
  float scale = rsqrtf(tot / (float)C + 1e-6f);
  for (int c = tid; c < C; c += 256) x[c] = x[c] * scale * gamma[c];
}

// ---------------------------------------------------------------------------
__global__ __launch_bounds__(256) void rope_q(
    float* __restrict__ q, const float* __restrict__ cosb, const float* __restrict__ sinb)
{
  int idx = blockIdx.x * 256 + threadIdx.x;
  int i = idx & 31;
  int h = (idx >> 5) & 15;
  int m = idx >> 9;
  float* x = q + (size_t)m * 3072 + h * 192 + 128;
  const float* cb = cosb + (size_t)m * 64;
  const float* sb = sinb + (size_t)m * 64;
  float x1 = x[i], x2 = x[i + 32];
  x[i]      = x1 * cb[i]      - x2 * sb[i];
  x[i + 32] = x2 * cb[i + 32] + x1 * sb[i + 32];
}

__global__ __launch_bounds__(256) void rope_k(
    float* __restrict__ kvb, const float* __restrict__ cosb, const float* __restrict__ sinb)
{
  int idx = blockIdx.x * 256 + threadIdx.x;
  int i = idx & 31;
  int m = idx >> 5;
  float* x = kvb + (size_t)m * 576 + 512;
  const float* cb = cosb + (size_t)m * 64;
  const float* sb = sinb + (size_t)m * 64;
  float x1 = x[i], x2 = x[i + 32];
  x[i]      = x1 * cb[i]      - x2 * sb[i];
  x[i + 32] = x2 * cb[i + 32] + x1 * sb[i + 32];
}

// ---------------------------------------------------------------------------
// Pack kernels: build bf16 Q (b,h,s,192) pre-scaled; bf16 K (b,h,s,192);
// bf16 V^T (b,h,128,s).
// ---------------------------------------------------------------------------
__global__ __launch_bounds__(256) void pack_q(
    const float* __restrict__ qbuf, short* __restrict__ Qb)
{
  int m = blockIdx.x;             // 0..4095
  int b = m >> 11, s = m & 2047;
  for (int i = threadIdx.x; i < 3072; i += 256) {
    int h = i / 192, c = i - h * 192;
    Qb[(((size_t)(b * 16 + h)) * 2048 + s) * 192 + c] =
        f2bf(qbuf[(size_t)m * 3072 + i] * SCALE_F);
  }
}

__global__ __launch_bounds__(256) void pack_k(
    const float* __restrict__ kvx, const float* __restrict__ kvb,
    short* __restrict__ Kb)
{
  int m = blockIdx.x;
  int b = m >> 11, s = m & 2047;
  for (int i = threadIdx.x; i < 3072; i += 256) {
    int h = i / 192, c = i - h * 192;
    float v = (c < 128) ? kvx[((size_t)m * 16 + h) * 256 + c]
                        : kvb[(size_t)m * 576 + 512 + (c - 128)];
    Kb[(((size_t)(b * 16 + h)) * 2048 + s) * 192 + c] = f2bf(v);
  }
}

__global__ __launch_bounds__(256) void pack_vt(
    const float* __restrict__ kvx, short* __restrict__ Vt)
{
  __shared__ float t[32][33];
  int s0 = blockIdx.x * 32, v0 = blockIdx.y * 32, bh = blockIdx.z;
  int b = bh >> 4, h = bh & 15;
  int c = threadIdx.x & 31, r4 = threadIdx.x >> 5;   // 8 rows per pass
  #pragma unroll
  for (int rr = 0; rr < 32; rr += 8) {
    int s = s0 + rr + r4;
    t[rr + r4][c] = kvx[(((size_t)(b * 2048 + s)) * 16 + h) * 256 + 128 + v0 + c];
  }
  __syncthreads();
  #pragma unroll
  for (int rr = 0; rr < 32; rr += 8) {
    int v = v0 + rr + r4;
    Vt[((size_t)bh * 128 + v) * 2048 + s0 + c] = f2bf(t[c][rr + r4]);
  }
}

// ---------------------------------------------------------------------------
// MFMA flash attention. Block = (q-tile 64, head, batch); 4 waves x 16 q-rows.
// Qb: (b,h,s,192) bf16 pre-scaled. Kb: (b,h,s,192) bf16. Vt: (b,h,128,s) bf16.
// attn out: (m, h, 128) fp32.
// Layouts (HW-verified): A-frag A[m=lane&15][k=quad*8+j]; B-frag from [N][K]
// matrix loads identically; C/D col=lane&15, row=quad*4+reg.
// ---------------------------------------------------------------------------
#define KSTR 200   // bf16 units; 400B row: 16B-aligned, 2-way bank alias (free)
#define VSTR 72    // 144B row
#define PSTR 72

__global__ __launch_bounds__(256) void flash_mfma(
    const short* __restrict__ Qb, const short* __restrict__ Kb,
    const short* __restrict__ Vt, float* __restrict__ attn)
{
  __shared__ __align__(16) short Ks[64 * KSTR];    // 25.6 KB
  __shared__ __align__(16) short Vs[128 * VSTR];   // 18.4 KB
  __shared__ __align__(16) short Ps[4][16 * PSTR]; // 9.2 KB

  const int qt = blockIdx.x, h = blockIdx.y, b = blockIdx.z;
  const int bh = b * 16 + h;
  const int tid = threadIdx.x;
  const int wave = tid >> 6, lane = tid & 63;
  const int quad = lane >> 4, n16 = lane & 15;
  const int q0 = qt * 64;
  const int qw = q0 + wave * 16;

  // Q A-frags: 16 rows x 192, row m = n16, k-slice t*32 + quad*8..+7
  bf16x8 aQ[6];
  {
    const short* qp = Qb + ((size_t)bh * 2048 + qw + n16) * 192 + quad * 8;
    #pragma unroll
    for (int t = 0; t < 6; ++t)
      aQ[t] = *(const bf16x8*)(qp + t * 32);
  }

  f32x4 O[8];
  #pragma unroll
  for (int i = 0; i < 8; ++i) O[i] = (f32x4){0.f, 0.f, 0.f, 0.f};
  float m_i[4], l_i[4];
  #pragma unroll
  for (int r = 0; r < 4; ++r) { m_i[r] = NEG_BIG; l_i[r] = 0.f; }

  short* pw = &Ps[wave][0];

  for (int kt = 0; kt <= qt; ++kt) {
    // ---- stage K (64x192) and V^T (128x64) tiles ----
    {
      const short* src = Kb + ((size_t)bh * 2048 + kt * 64) * 192;
      for (int i = tid; i < 64 * 24; i += 256) {
        int r = i / 24, c = (i - r * 24) * 8;
        *(bf16x8*)&Ks[r * KSTR + c] = *(const bf16x8*)(src + r * 192 + c);
      }
      const short* vsrc = Vt + (size_t)bh * 128 * 2048 + kt * 64;
      for (int i = tid; i < 128 * 8; i += 256) {
        int v = i >> 3, c = (i & 7) * 8;
        *(bf16x8*)&Vs[v * VSTR + c] = *(const bf16x8*)(vsrc + (size_t)v * 2048 + c);
      }
    }
    __syncthreads();

    // ---- scores: 16x64 per wave, 4 col-tiles of 16 keys ----
    float s[4][4];
    #pragma unroll
    for (int ct = 0; ct < 4; ++ct) {
      if (kt * 64 + ct * 16 <= qw + 15) {       // tile has >=1 unmasked col
        f32x4 acc = (f32x4){0.f, 0.f, 0.f, 0.f};
        const short* kp = &Ks[(ct * 16 + n16) * KSTR + quad * 8];
        #pragma unroll
        for (int t = 0; t < 6; ++t) {
          bf16x8 bk = *(const bf16x8*)(kp + t * 32);
          acc = __builtin_amdgcn_mfma_f32_16x16x32_bf16(aQ[t], bk, acc, 0, 0, 0);
        }
        #pragma unroll
        for (int r = 0; r < 4; ++r) s[ct][r] = acc[r];
        if (kt == qt) {                          // per-element causal mask
          int key = kt * 64 + ct * 16 + n16;
          #pragma unroll
          for (int r = 0; r < 4; ++r)
            if (key > qw + quad * 4 + r) s[ct][r] = NEG_BIG;
        }
      } else {
        #pragma unroll
        for (int r = 0; r < 4; ++r) s[ct][r] = NEG_BIG;
      }
    }

    // ---- online softmax (per wave, rows quad*4+r, data across 16 lanes) ----
    float alpha[4];
    #pragma unroll
    for (int r = 0; r < 4; ++r) {
      float mx = fmaxf(fmaxf(s[0][r], s[1][r]), fmaxf(s[2][r], s[3][r]));
      mx = fmaxf(mx, __shfl_xor(mx, 1));
      mx = fmaxf(mx, __shfl_xor(mx, 2));
      mx = fmaxf(mx, __shfl_xor(mx, 4));
      mx = fmaxf(mx, __shfl_xor(mx, 8));
      float mnew = fmaxf(m_i[r], mx);
      alpha[r] = __expf(m_i[r] - mnew);
      m_i[r] = mnew;
      float rs = 0.f;
      #pragma unroll
      for (int ct = 0; ct < 4; ++ct) {
        float p = __expf(s[ct][r] - mnew);
        s[ct][r] = p;
        rs += p;
      }
      rs += __shfl_xor(rs, 1);
      rs += __shfl_xor(rs, 2);
      rs += __shfl_xor(rs, 4);
      rs += __shfl_xor(rs, 8);
      l_i[r] = l_i[r] * alpha[r] + rs;
    }

    // rescale O
    #pragma unroll
    for (int vt = 0; vt < 8; ++vt)
      #pragma unroll
      for (int r = 0; r < 4; ++r) O[vt][r] *= alpha[r];

    // ---- P -> bf16 -> per-wave LDS (C-layout write, A-layout read) ----
    #pragma unroll
    for (int ct = 0; ct < 4; ++ct)
      #pragma unroll
      for (int r = 0; r < 4; ++r)
        pw[(quad * 4 + r) * PSTR + ct * 16 + n16] = f2bf(s[ct][r]);

    // ---- PV: O[16x128] += P[16x64] @ V[64x128] ----
    #pragma unroll
    for (int ks = 0; ks < 2; ++ks) {
      if (kt * 64 + ks * 32 <= qw + 15) {
        bf16x8 aP = *(const bf16x8*)&pw[n16 * PSTR + ks * 32 + quad * 8];
        #pragma unroll
        for (int vt = 0; vt < 8; ++vt) {
          bf16x8 bV = *(const bf16x8*)&Vs[(vt * 16 + n16) * VSTR + ks * 32 + quad * 8];
          O[vt] = __builtin_amdgcn_mfma_f32_16x16x32_bf16(aP, bV, O[vt], 0, 0, 0);
        }
      }
    }
    __syncthreads();
  }

  // ---- epilogue: O / l, write fp32 attn (m,16,128) ----
  float inv_l[4];
  #pragma unroll
  for (int r = 0; r < 4; ++r) inv_l[r] = 1.f / l_i[r];
  #pragma unroll
  for (int vt = 0; vt < 8; ++vt)
    #pragma unroll
    for (int r = 0; r < 4; ++r) {
      size_t m = (size_t)b * 2048 + qw + quad * 4 + r;
      attn[(m * 16 + h) * 128 + vt * 16 + n16] = O[vt][r] * inv_l[r];
    }
}

// ---------------------------------------------------------------------------
extern "C" void kernel_launch(void* const* d_in, const int* in_sizes, int n_in,
                              void* d_out, int out_size, void* d_ws, size_t ws_size,
                              hipStream_t stream)
{
  const float* hidden   = (const float*)d_in[0];
  const float* cosb     = (const float*)d_in[1];
  const float* sinb     = (const float*)d_in[2];
  const float* Wq_down  = (const float*)d_in[3];
  const float* q_gamma  = (const float*)d_in[4];
  const float* Wq_up    = (const float*)d_in[5];
  const float* Wkv_down = (const float*)d_in[6];
  const float* kv_gamma = (const float*)d_in[7];
  const float* Wkv_up   = (const float*)d_in[8];
  const float* Wo       = (const float*)d_in[9];
  float* out = (float*)d_out;

  float* p = (float*)d_ws;
  float* q_lat = p;  p += (size_t)4096 * 1536;
  float* kvbuf = p;  p += (size_t)4096 * 576;
  float* qbuf  = p;  p += (size_t)4096 * 3072;
  float* kvx   = p;  p += (size_t)4096 * 4096;

  // bf16 aliases (written only after their fp32 hosts are dead):
  short* Qb = (short*)q_lat;                 // 12.58M shorts, q_lat dead post-gemm6
  short* Kb = (short*)qbuf;                  // 12.58M shorts, qbuf dead post-pack_q
  short* Vt = (short*)(qbuf + (size_t)4096 * 1536);  // 8.39M shorts
  float* attn = kvx;                         // kvx dead post-pack_k/pack_vt

  dim3 blk(256);

  // 1) q_lat = hidden @ Wq_down^T          (4096,1536) K=2048
  gemm_at<<<dim3(1536 / 64, 4096 / 64), blk, 0, stream>>>(hidden, 2048, Wq_down, q_lat, 1536, 2048);
  // 2) kv = hidden @ Wkv_down^T            (4096,576)  K=2048
  gemm_at<<<dim3(576 / 64, 4096 / 64), blk, 0, stream>>>(hidden, 2048, Wkv_down, kvbuf, 576, 2048);
  // 3) rmsnorm(q_lat)
  rmsnorm_rows<<<4096, blk, 0, stream>>>(q_lat, q_gamma, 1536, 1536);
  // 4) rmsnorm(c_kv)
  rmsnorm_rows<<<4096, blk, 0, stream>>>(kvbuf, kv_gamma, 512, 576);
  // 5) rope on shared k_rope
  rope_k<<<(4096 * 32) / 256, blk, 0, stream>>>(kvbuf, cosb, sinb);
  // 6) qbuf = q_lat @ Wq_up^T              (4096,3072) K=1536
  gemm_at<<<dim3(3072 / 64, 4096 / 64), blk, 0, stream>>>(q_lat, 1536, Wq_up, qbuf, 3072, 1536);
  // 7) rope on q
  rope_q<<<(4096 * 16 * 32) / 256, blk, 0, stream>>>(qbuf, cosb, sinb);
  // 8) kvx = c_kv @ Wkv_up^T               (4096,4096) K=512
  gemm_at<<<dim3(4096 / 64, 4096 / 64), blk, 0, stream>>>(kvbuf, 576, Wkv_up, kvx, 4096, 512);
  // 9) bf16 packs (order matters: pack_q frees qbuf for Kb/Vt aliases)
  pack_q<<<4096, blk, 0, stream>>>(qbuf, Qb);
  pack_k<<<4096, blk, 0, stream>>>(kvx, kvbuf, Kb);
  pack_vt<<<dim3(64, 4, 32), blk, 0, stream>>>(kvx, Vt);
  // 10) MFMA flash attention -> attn (m,16,128) fp32
  flash_mfma<<<dim3(32, 16, 2), blk, 0, stream>>>(Qb, Kb, Vt, attn);
  // 11) out = attn @ Wo^T                  (4096,2048) K=2048
  gemm_at<<<dim3(2048 / 64, 4096 / 64), blk, 0, stream>>>(attn, 2048, Wo, out, 2048, 2048);
}

// Round 3
// 775.301 us; speedup vs baseline: 6.1573x; 2.9016x over previous
//
#include <hip/hip_runtime.h>
#include <math.h>

#define SCALE_F 0.0721687836487032f  // 192^-0.5
#define NEG_BIG -3.0e38f

typedef __attribute__((ext_vector_type(8))) short bf16x8;
typedef __attribute__((ext_vector_type(4))) float f32x4;

static __device__ __forceinline__ short f2bf(float f) {
  unsigned u = __float_as_uint(f);
  u += 0x7fffu + ((u >> 16) & 1u);   // RNE
  return (short)(u >> 16);
}
static __device__ __forceinline__ float bf2f(short s) {
  return __uint_as_float(((unsigned)(unsigned short)s) << 16);
}

// async global->LDS, 16B per lane (m97-verified path)
static __device__ __forceinline__ void gl_lds16(const void* g, void* l) {
  __builtin_amdgcn_global_load_lds((const __attribute__((address_space(1))) void*)g,
                                   (__attribute__((address_space(3))) void*)l, 16, 0, 0);
}

// ---------------------------------------------------------------------------
// bf16 MFMA GEMM (m97 structure): C[M,N] = A[M,K] @ W[N,K]^T
// 128x128 tile, BK=32, 256 thr (4 waves, each 64x64 via 4x4 frags of 16x16x32).
// A,W bf16 row-major [.][K]; C fp32 or bf16 per template.
// Layouts (HW-verified m89/m90/m97): A/B frag = tile[n16][quad*8..+7];
// C/D col=n16, row=quad*4+reg.
// ---------------------------------------------------------------------------
template <bool BF16_OUT>
__global__ __launch_bounds__(256) void gemm_mfma(
    const short* __restrict__ A, const short* __restrict__ W,
    void* __restrict__ Cout, int N, int K)
{
  __shared__ __align__(16) short As[128 * 32];   // 8 KB, [row][k] no pad (lds-dma)
  __shared__ __align__(16) short Ws[128 * 32];   // 8 KB
  const int tid = threadIdx.x;
  const int lane = tid & 63;
  const int quad = lane >> 4, n16 = lane & 15;
  const int bm = blockIdx.y * 128, bn = blockIdx.x * 128;
  const int wr = ((tid >> 6) >> 1) * 64, wc = ((tid >> 6) & 1) * 64;

  f32x4 acc[4][4];
  #pragma unroll
  for (int i = 0; i < 4; ++i)
    #pragma unroll
    for (int j = 0; j < 4; ++j) acc[i][j] = (f32x4){0.f, 0.f, 0.f, 0.f};

  const int r0 = tid >> 2, c0 = (tid & 3) * 8;   // loader: chunk0 row r0, k-off c0
  const short* a0p = A + (size_t)(bm + r0) * K + c0;
  const short* a1p = A + (size_t)(bm + 64 + r0) * K + c0;
  const short* w0p = W + (size_t)(bn + r0) * K + c0;
  const short* w1p = W + (size_t)(bn + 64 + r0) * K + c0;
  short* asd0 = &As[tid * 8];          // lane-linear LDS dests (wave-uniform+lane*16)
  short* asd1 = &As[2048 + tid * 8];
  short* wsd0 = &Ws[tid * 8];
  short* wsd1 = &Ws[2048 + tid * 8];

  for (int k0 = 0; k0 < K; k0 += 32) {
    gl_lds16(a0p, asd0);
    gl_lds16(a1p, asd1);
    gl_lds16(w0p, wsd0);
    gl_lds16(w1p, wsd1);
    a0p += 32; a1p += 32; w0p += 32; w1p += 32;
    __syncthreads();

    bf16x8 af[4], wf[4];
    #pragma unroll
    for (int i = 0; i < 4; ++i) {
      af[i] = *(const bf16x8*)&As[(wr + i * 16 + n16) * 32 + quad * 8];
      wf[i] = *(const bf16x8*)&Ws[(wc + i * 16 + n16) * 32 + quad * 8];
    }
    #pragma unroll
    for (int i = 0; i < 4; ++i)
      #pragma unroll
      for (int j = 0; j < 4; ++j)
        acc[i][j] = __builtin_amdgcn_mfma_f32_16x16x32_bf16(af[i], wf[j], acc[i][j], 0, 0, 0);
    __syncthreads();
  }

  #pragma unroll
  for (int i = 0; i < 4; ++i) {
    #pragma unroll
    for (int r = 0; r < 4; ++r) {
      size_t row = (size_t)(bm + wr + i * 16 + quad * 4 + r);
      #pragma unroll
      for (int j = 0; j < 4; ++j) {
        int col = bn + wc + j * 16 + n16;
        if (BF16_OUT) ((short*)Cout)[row * N + col] = f2bf(acc[i][j][r]);
        else          ((float*)Cout)[row * N + col] = acc[i][j][r];
      }
    }
  }
}

// ---------------------------------------------------------------------------
// fp32 -> bf16 casts
// ---------------------------------------------------------------------------
__global__ __launch_bounds__(256) void cast_bf16(
    const float* __restrict__ src, short* __restrict__ dst, int n)
{
  int i = (blockIdx.x * 256 + threadIdx.x) * 4;
  if (i < n) {
    float4 v = *(const float4*)(src + i);
    short4 o = { f2bf(v.x), f2bf(v.y), f2bf(v.z), f2bf(v.w) };
    *(short4*)(dst + i) = o;
  }
}

// pad rows [srcRows..dstRows) with zeros; cols fixed 2048
__global__ __launch_bounds__(256) void cast_bf16_pad(
    const float* __restrict__ src, short* __restrict__ dst, int srcRows)
{
  int i = (blockIdx.x * 256 + threadIdx.x) * 4;
  int r = i >> 11;
  short4 o = {0, 0, 0, 0};
  if (r < srcRows) {
    float4 v = *(const float4*)(src + i);
    o.x = f2bf(v.x); o.y = f2bf(v.y); o.z = f2bf(v.z); o.w = f2bf(v.w);
  }
  *(short4*)(dst + i) = o;
}

// ---------------------------------------------------------------------------
// RMSNorm (fp32 in) -> bf16 out
// ---------------------------------------------------------------------------
__global__ __launch_bounds__(256) void rmsnorm_cast(
    const float* __restrict__ X, const float* __restrict__ gamma,
    short* __restrict__ Y, int C, int sx, int sy)
{
  const float* x = X + (size_t)blockIdx.x * sx;
  short* y = Y + (size_t)blockIdx.x * sy;
  const int tid = threadIdx.x;
  float ss = 0.f;
  for (int c = tid * 4; c < C; c += 1024) {
    float4 v = *(const float4*)(x + c);
    ss += v.x * v.x + v.y * v.y + v.z * v.z + v.w * v.w;
  }
  #pragma unroll
  for (int off = 32; off > 0; off >>= 1) ss += __shfl_down(ss, off, 64);
  __shared__ float red[4];
  if ((tid & 63) == 0) red[tid >> 6] = ss;
  __syncthreads();
  float tot = red[0] + red[1] + red[2] + red[3];
  float scale = rsqrtf(tot / (float)C + 1e-6f);
  for (int c = tid * 4; c < C; c += 1024) {
    float4 v = *(const float4*)(x + c);
    float4 g = *(const float4*)(gamma + c);
    short4 o = { f2bf(v.x * scale * g.x), f2bf(v.y * scale * g.y),
                 f2bf(v.z * scale * g.z), f2bf(v.w * scale * g.w) };
    *(short4*)(y + c) = o;
  }
}

// ---------------------------------------------------------------------------
// rope k_rope (fp32 kv cols 512..575, stride 640) -> bf16 [m][64]
// ---------------------------------------------------------------------------
__global__ __launch_bounds__(256) void rope_k_cast(
    const float* __restrict__ kv, const float* __restrict__ cosb,
    const float* __restrict__ sinb, short* __restrict__ kr)
{
  int idx = blockIdx.x * 256 + threadIdx.x;   // 4096*32
  int i = idx & 31, m = idx >> 5;
  const float* x = kv + (size_t)m * 640 + 512;
  const float* cb = cosb + (size_t)m * 64;
  const float* sb = sinb + (size_t)m * 64;
  float x1 = x[i], x2 = x[i + 32];
  kr[(size_t)m * 64 + i]      = f2bf(x1 * cb[i] - x2 * sb[i]);
  kr[(size_t)m * 64 + i + 32] = f2bf(x2 * cb[i + 32] + x1 * sb[i + 32]);
}

// ---------------------------------------------------------------------------
// q (bf16 [m][3072]) -> rope + scale -> Qb (b,h,s,192) bf16
// ---------------------------------------------------------------------------
__global__ __launch_bounds__(256) void rope_pack_q(
    const short* __restrict__ q3, const float* __restrict__ cosb,
    const float* __restrict__ sinb, short* __restrict__ Qb)
{
  int m = blockIdx.x;
  int b = m >> 11, s = m & 2047;
  for (int i = threadIdx.x; i < 3072; i += 256) {
    int h = i / 192, c = i - h * 192;
    float v;
    if (c < 128) {
      v = bf2f(q3[(size_t)m * 3072 + i]);
    } else {
      int j = c - 128;
      float cs = cosb[(size_t)m * 64 + j], sn = sinb[(size_t)m * 64 + j];
      float xc = bf2f(q3[(size_t)m * 3072 + i]);
      if (j < 32) { float x2 = bf2f(q3[(size_t)m * 3072 + i + 32]); v = xc * cs - x2 * sn; }
      else        { float x1 = bf2f(q3[(size_t)m * 3072 + i - 32]); v = xc * cs + x1 * sn; }
    }
    Qb[(((size_t)(b * 16 + h)) * 2048 + s) * 192 + c] = f2bf(v * SCALE_F);
  }
}

// ---------------------------------------------------------------------------
// Kb (b,h,s,192) from kvx_b nope (bf16) + krope_b broadcast (bf16)
// ---------------------------------------------------------------------------
__global__ __launch_bounds__(256) void pack_k_b(
    const short* __restrict__ kvx, const short* __restrict__ kr, short* __restrict__ Kb)
{
  int m = blockIdx.x;
  int b = m >> 11, s = m & 2047;
  for (int i = threadIdx.x; i < 3072; i += 256) {
    int h = i / 192, c = i - h * 192;
    short v = (c < 128) ? kvx[((size_t)m * 16 + h) * 256 + c]
                        : kr[(size_t)m * 64 + (c - 128)];
    Kb[(((size_t)(b * 16 + h)) * 2048 + s) * 192 + c] = v;
  }
}

// V^T (b,h,128,2048) bf16 from kvx_b
__global__ __launch_bounds__(256) void pack_vt_b(
    const short* __restrict__ kvx, short* __restrict__ Vt)
{
  __shared__ short t[32][34];
  int s0 = blockIdx.x * 32, v0 = blockIdx.y * 32, bh = blockIdx.z;
  int b = bh >> 4, h = bh & 15;
  int c = threadIdx.x & 31, r4 = threadIdx.x >> 5;
  #pragma unroll
  for (int rr = 0; rr < 32; rr += 8) {
    int s = s0 + rr + r4;
    t[rr + r4][c] = kvx[(((size_t)(b * 2048 + s)) * 16 + h) * 256 + 128 + v0 + c];
  }
  __syncthreads();
  #pragma unroll
  for (int rr = 0; rr < 32; rr += 8) {
    int v = v0 + rr + r4;
    Vt[((size_t)bh * 128 + v) * 2048 + s0 + c] = t[c][rr + r4];
  }
}

// ---------------------------------------------------------------------------
// MFMA flash attention (round-2 verified), epilogue now writes bf16.
// ---------------------------------------------------------------------------
#define KSTR 200
#define VSTR 72
#define PSTR 72

__global__ __launch_bounds__(256) void flash_mfma(
    const short* __restrict__ Qb, const short* __restrict__ Kb,
    const short* __restrict__ Vt, short* __restrict__ attnb)
{
  __shared__ __align__(16) short Ks[64 * KSTR];
  __shared__ __align__(16) short Vs[128 * VSTR];
  __shared__ __align__(16) short Ps[4][16 * PSTR];

  const int qt = blockIdx.x, h = blockIdx.y, b = blockIdx.z;
  const int bh = b * 16 + h;
  const int tid = threadIdx.x;
  const int wave = tid >> 6, lane = tid & 63;
  const int quad = lane >> 4, n16 = lane & 15;
  const int qw = qt * 64 + wave * 16;

  bf16x8 aQ[6];
  {
    const short* qp = Qb + ((size_t)bh * 2048 + qw + n16) * 192 + quad * 8;
    #pragma unroll
    for (int t = 0; t < 6; ++t) aQ[t] = *(const bf16x8*)(qp + t * 32);
  }

  f32x4 O[8];
  #pragma unroll
  for (int i = 0; i < 8; ++i) O[i] = (f32x4){0.f, 0.f, 0.f, 0.f};
  float m_i[4], l_i[4];
  #pragma unroll
  for (int r = 0; r < 4; ++r) { m_i[r] = NEG_BIG; l_i[r] = 0.f; }

  short* pw = &Ps[wave][0];

  for (int kt = 0; kt <= qt; ++kt) {
    {
      const short* src = Kb + ((size_t)bh * 2048 + kt * 64) * 192;
      for (int i = tid; i < 64 * 24; i += 256) {
        int r = i / 24, c = (i - r * 24) * 8;
        *(bf16x8*)&Ks[r * KSTR + c] = *(const bf16x8*)(src + r * 192 + c);
      }
      const short* vsrc = Vt + (size_t)bh * 128 * 2048 + kt * 64;
      for (int i = tid; i < 128 * 8; i += 256) {
        int v = i >> 3, c = (i & 7) * 8;
        *(bf16x8*)&Vs[v * VSTR + c] = *(const bf16x8*)(vsrc + (size_t)v * 2048 + c);
      }
    }
    __syncthreads();

    float s[4][4];
    #pragma unroll
    for (int ct = 0; ct < 4; ++ct) {
      if (kt * 64 + ct * 16 <= qw + 15) {
        f32x4 acc = (f32x4){0.f, 0.f, 0.f, 0.f};
        const short* kp = &Ks[(ct * 16 + n16) * KSTR + quad * 8];
        #pragma unroll
        for (int t = 0; t < 6; ++t) {
          bf16x8 bk = *(const bf16x8*)(kp + t * 32);
          acc = __builtin_amdgcn_mfma_f32_16x16x32_bf16(aQ[t], bk, acc, 0, 0, 0);
        }
        #pragma unroll
        for (int r = 0; r < 4; ++r) s[ct][r] = acc[r];
        if (kt == qt) {
          int key = kt * 64 + ct * 16 + n16;
          #pragma unroll
          for (int r = 0; r < 4; ++r)
            if (key > qw + quad * 4 + r) s[ct][r] = NEG_BIG;
        }
      } else {
        #pragma unroll
        for (int r = 0; r < 4; ++r) s[ct][r] = NEG_BIG;
      }
    }

    float alpha[4];
    #pragma unroll
    for (int r = 0; r < 4; ++r) {
      float mx = fmaxf(fmaxf(s[0][r], s[1][r]), fmaxf(s[2][r], s[3][r]));
      mx = fmaxf(mx, __shfl_xor(mx, 1));
      mx = fmaxf(mx, __shfl_xor(mx, 2));
      mx = fmaxf(mx, __shfl_xor(mx, 4));
      mx = fmaxf(mx, __shfl_xor(mx, 8));
      float mnew = fmaxf(m_i[r], mx);
      alpha[r] = __expf(m_i[r] - mnew);
      m_i[r] = mnew;
      float rs = 0.f;
      #pragma unroll
      for (int ct = 0; ct < 4; ++ct) {
        float p = __expf(s[ct][r] - mnew);
        s[ct][r] = p;
        rs += p;
      }
      rs += __shfl_xor(rs, 1);
      rs += __shfl_xor(rs, 2);
      rs += __shfl_xor(rs, 4);
      rs += __shfl_xor(rs, 8);
      l_i[r] = l_i[r] * alpha[r] + rs;
    }

    #pragma unroll
    for (int vt = 0; vt < 8; ++vt)
      #pragma unroll
      for (int r = 0; r < 4; ++r) O[vt][r] *= alpha[r];

    #pragma unroll
    for (int ct = 0; ct < 4; ++ct)
      #pragma unroll
      for (int r = 0; r < 4; ++r)
        pw[(quad * 4 + r) * PSTR + ct * 16 + n16] = f2bf(s[ct][r]);

    #pragma unroll
    for (int ks = 0; ks < 2; ++ks) {
      if (kt * 64 + ks * 32 <= qw + 15) {
        bf16x8 aP = *(const bf16x8*)&pw[n16 * PSTR + ks * 32 + quad * 8];
        #pragma unroll
        for (int vt = 0; vt < 8; ++vt) {
          bf16x8 bV = *(const bf16x8*)&Vs[(vt * 16 + n16) * VSTR + ks * 32 + quad * 8];
          O[vt] = __builtin_amdgcn_mfma_f32_16x16x32_bf16(aP, bV, O[vt], 0, 0, 0);
        }
      }
    }
    __syncthreads();
  }

  float inv_l[4];
  #pragma unroll
  for (int r = 0; r < 4; ++r) inv_l[r] = 1.f / l_i[r];
  #pragma unroll
  for (int vt = 0; vt < 8; ++vt)
    #pragma unroll
    for (int r = 0; r < 4; ++r) {
      size_t m = (size_t)b * 2048 + qw + quad * 4 + r;
      attnb[(m * 16 + h) * 128 + vt * 16 + n16] = f2bf(O[vt][r] * inv_l[r]);
    }
}

// ---------------------------------------------------------------------------
extern "C" void kernel_launch(void* const* d_in, const int* in_sizes, int n_in,
                              void* d_out, int out_size, void* d_ws, size_t ws_size,
                              hipStream_t stream)
{
  const float* hidden   = (const float*)d_in[0];
  const float* cosb     = (const float*)d_in[1];
  const float* sinb     = (const float*)d_in[2];
  const float* Wq_down  = (const float*)d_in[3];
  const float* q_gamma  = (const float*)d_in[4];
  const float* Wq_up    = (const float*)d_in[5];
  const float* Wkv_down = (const float*)d_in[6];
  const float* kv_gamma = (const float*)d_in[7];
  const float* Wkv_up   = (const float*)d_in[8];
  const float* Wo       = (const float*)d_in[9];
  float* out = (float*)d_out;

  // ---- workspace layout (151 MB, aliased regions; liveness verified) ----
  char* base = (char*)d_ws;
  // region A (27.26 MB): hb + kvf32, later overlaid by Qb
  short* hb  = (short*)base;                               // 4096x2048 bf16
  float* kvf = (float*)(base + 16777216);                  // 4096x640 fp32
  short* Qb  = (short*)base;                               // (b,h,s,192) bf16
  char* pB = base + 27262976;
  // region B (30.93 MB): weights bf16
  short* Wqd_b  = (short*)pB;                              // 1536x2048
  short* Wkvd_b = (short*)(pB + 6291456);                  // 640x2048 (padded)
  short* Wqu_b  = (short*)(pB + 8912896);                  // 3072x1536
  short* Wkvu_b = (short*)(pB + 18350080);                 // 4096x512
  short* Wo_b   = (short*)(pB + 22544384);                 // 2048x2048
  char* pC = pB + 30932992;
  // region C (25.17 MB): q_lat f32 -> qb3 bf16 -> Kb bf16
  float* q_lat = (float*)pC;                               // 4096x1536 fp32
  short* qb3   = (short*)pC;                               // 4096x3072 bf16
  short* Kb    = (short*)pC;                               // (b,h,s,192) bf16
  char* pD = pC + 25165824;
  // region D (17.3 MB): q_lat_b + ckv_b + krope_b -> attn_b
  short* q_lat_b = (short*)pD;                             // 4096x1536
  short* ckv_b   = (short*)(pD + 12582912);                // 4096x512
  short* krope_b = (short*)(pD + 16777216);                // 4096x64
  short* attn_b  = (short*)pD;                             // 4096x2048 bf16
  char* pE = pD + 17301504;
  short* kvx_b = (short*)pE;                               // 4096x4096 bf16
  char* pF = pE + 33554432;
  short* Vt = (short*)pF;                                  // (b,h,128,2048) bf16

  dim3 blk(256);

  // ---- casts ----
  cast_bf16<<<8192, blk, 0, stream>>>(hidden, hb, 4096 * 2048);
  cast_bf16<<<3072, blk, 0, stream>>>(Wq_down, Wqd_b, 1536 * 2048);
  cast_bf16_pad<<<1280, blk, 0, stream>>>(Wkv_down, Wkvd_b, 576);
  cast_bf16<<<4608, blk, 0, stream>>>(Wq_up, Wqu_b, 3072 * 1536);
  cast_bf16<<<2048, blk, 0, stream>>>(Wkv_up, Wkvu_b, 4096 * 512);
  cast_bf16<<<4096, blk, 0, stream>>>(Wo, Wo_b, 2048 * 2048);

  // ---- down-proj GEMMs (fp32 out, feeds rmsnorm) ----
  gemm_mfma<false><<<dim3(12, 32), blk, 0, stream>>>(hb, Wqd_b, q_lat, 1536, 2048);
  gemm_mfma<false><<<dim3(5, 32), blk, 0, stream>>>(hb, Wkvd_b, kvf, 640, 2048);

  // ---- norms + k-rope ----
  rmsnorm_cast<<<4096, blk, 0, stream>>>(q_lat, q_gamma, q_lat_b, 1536, 1536, 1536);
  rmsnorm_cast<<<4096, blk, 0, stream>>>(kvf, kv_gamma, ckv_b, 512, 640, 512);
  rope_k_cast<<<(4096 * 32) / 256, blk, 0, stream>>>(kvf, cosb, sinb, krope_b);

  // ---- up-proj GEMMs (bf16 out) ----
  gemm_mfma<true><<<dim3(24, 32), blk, 0, stream>>>(q_lat_b, Wqu_b, qb3, 3072, 1536);
  rope_pack_q<<<4096, blk, 0, stream>>>(qb3, cosb, sinb, Qb);   // frees region C
  gemm_mfma<true><<<dim3(32, 32), blk, 0, stream>>>(ckv_b, Wkvu_b, kvx_b, 4096, 512);
  pack_k_b<<<4096, blk, 0, stream>>>(kvx_b, krope_b, Kb);
  pack_vt_b<<<dim3(64, 4, 32), blk, 0, stream>>>(kvx_b, Vt);

  // ---- attention (bf16 out) + output proj ----
  flash_mfma<<<dim3(32, 16, 2), blk, 0, stream>>>(Qb, Kb, Vt, attn_b);
  gemm_mfma<false><<<dim3(16, 32), blk, 0, stream>>>(attn_b, Wo_b, out, 2048, 2048);
}

// Round 4
// 653.621 us; speedup vs baseline: 7.3035x; 1.1862x over previous
//
#include <hip/hip_runtime.h>
#include <math.h>

#define SCALE_F 0.0721687836487032f  // 192^-0.5
#define NEG_BIG -3.0e38f

typedef __attribute__((ext_vector_type(8))) short bf16x8;
typedef __attribute__((ext_vector_type(4))) float f32x4;

static __device__ __forceinline__ short f2bf(float f) {
  unsigned u = __float_as_uint(f);
  u += 0x7fffu + ((u >> 16) & 1u);   // RNE
  return (short)(u >> 16);
}
static __device__ __forceinline__ float bf2f(short s) {
  return __uint_as_float(((unsigned)(unsigned short)s) << 16);
}

// async global->LDS, 16B per lane (m97-verified path)
static __device__ __forceinline__ void gl_lds16(const void* g, void* l) {
  __builtin_amdgcn_global_load_lds((const __attribute__((address_space(1))) void*)g,
                                   (__attribute__((address_space(3))) void*)l, 16, 0, 0);
}

// ---------------------------------------------------------------------------
// bf16 MFMA GEMM (m97 structure): C[M,N] = A[M,K] @ W[N,K]^T
// ---------------------------------------------------------------------------
template <bool BF16_OUT>
__global__ __launch_bounds__(256) void gemm_mfma(
    const short* __restrict__ A, const short* __restrict__ W,
    void* __restrict__ Cout, int N, int K)
{
  __shared__ __align__(16) short As[128 * 32];
  __shared__ __align__(16) short Ws[128 * 32];
  const int tid = threadIdx.x;
  const int lane = tid & 63;
  const int quad = lane >> 4, n16 = lane & 15;
  const int bm = blockIdx.y * 128, bn = blockIdx.x * 128;
  const int wr = ((tid >> 6) >> 1) * 64, wc = ((tid >> 6) & 1) * 64;

  f32x4 acc[4][4];
  #pragma unroll
  for (int i = 0; i < 4; ++i)
    #pragma unroll
    for (int j = 0; j < 4; ++j) acc[i][j] = (f32x4){0.f, 0.f, 0.f, 0.f};

  const int r0 = tid >> 2, c0 = (tid & 3) * 8;
  const short* a0p = A + (size_t)(bm + r0) * K + c0;
  const short* a1p = A + (size_t)(bm + 64 + r0) * K + c0;
  const short* w0p = W + (size_t)(bn + r0) * K + c0;
  const short* w1p = W + (size_t)(bn + 64 + r0) * K + c0;
  short* asd0 = &As[tid * 8];
  short* asd1 = &As[2048 + tid * 8];
  short* wsd0 = &Ws[tid * 8];
  short* wsd1 = &Ws[2048 + tid * 8];

  for (int k0 = 0; k0 < K; k0 += 32) {
    gl_lds16(a0p, asd0);
    gl_lds16(a1p, asd1);
    gl_lds16(w0p, wsd0);
    gl_lds16(w1p, wsd1);
    a0p += 32; a1p += 32; w0p += 32; w1p += 32;
    __syncthreads();

    bf16x8 af[4], wf[4];
    #pragma unroll
    for (int i = 0; i < 4; ++i) {
      af[i] = *(const bf16x8*)&As[(wr + i * 16 + n16) * 32 + quad * 8];
      wf[i] = *(const bf16x8*)&Ws[(wc + i * 16 + n16) * 32 + quad * 8];
    }
    #pragma unroll
    for (int i = 0; i < 4; ++i)
      #pragma unroll
      for (int j = 0; j < 4; ++j)
        acc[i][j] = __builtin_amdgcn_mfma_f32_16x16x32_bf16(af[i], wf[j], acc[i][j], 0, 0, 0);
    __syncthreads();
  }

  #pragma unroll
  for (int i = 0; i < 4; ++i) {
    #pragma unroll
    for (int r = 0; r < 4; ++r) {
      size_t row = (size_t)(bm + wr + i * 16 + quad * 4 + r);
      #pragma unroll
      for (int j = 0; j < 4; ++j) {
        int col = bn + wc + j * 16 + n16;
        if (BF16_OUT) ((short*)Cout)[row * N + col] = f2bf(acc[i][j][r]);
        else          ((float*)Cout)[row * N + col] = acc[i][j][r];
      }
    }
  }
}

// ---------------------------------------------------------------------------
// fused fp32 -> bf16 cast of hidden + all 5 weights (one launch)
// segments: hidden 8192 | Wqd 3072 | Wqu 4608 | Wkvu 2048 | Wo 4096 | Wkvd(pad) 1280
// ---------------------------------------------------------------------------
__global__ __launch_bounds__(256) void cast_all(
    const float* __restrict__ hidden, const float* __restrict__ Wqd,
    const float* __restrict__ Wqu, const float* __restrict__ Wkvu,
    const float* __restrict__ Wo, const float* __restrict__ Wkvd,
    short* __restrict__ hb, short* __restrict__ Wqd_b, short* __restrict__ Wqu_b,
    short* __restrict__ Wkvu_b, short* __restrict__ Wo_b, short* __restrict__ Wkvd_b)
{
  int blk = blockIdx.x;
  const float* src; short* dst; int i;
  if (blk < 8192)       { src = hidden; dst = hb;     i = (blk * 256 + threadIdx.x) * 4; }
  else if (blk < 11264) { src = Wqd;  dst = Wqd_b;  i = ((blk - 8192) * 256 + threadIdx.x) * 4; }
  else if (blk < 15872) { src = Wqu;  dst = Wqu_b;  i = ((blk - 11264) * 256 + threadIdx.x) * 4; }
  else if (blk < 17920) { src = Wkvu; dst = Wkvu_b; i = ((blk - 15872) * 256 + threadIdx.x) * 4; }
  else if (blk < 22016) { src = Wo;   dst = Wo_b;   i = ((blk - 17920) * 256 + threadIdx.x) * 4; }
  else {
    i = ((blk - 22016) * 256 + threadIdx.x) * 4;
    int r = i >> 11;
    short4 o = {0, 0, 0, 0};
    if (r < 576) {
      float4 v = *(const float4*)(Wkvd + i);
      o.x = f2bf(v.x); o.y = f2bf(v.y); o.z = f2bf(v.z); o.w = f2bf(v.w);
    }
    *(short4*)(Wkvd_b + i) = o;
    return;
  }
  float4 v = *(const float4*)(src + i);
  short4 o = { f2bf(v.x), f2bf(v.y), f2bf(v.z), f2bf(v.w) };
  *(short4*)(dst + i) = o;
}

// ---------------------------------------------------------------------------
// RMSNorm (fp32 in) -> bf16 out (q branch)
// ---------------------------------------------------------------------------
__global__ __launch_bounds__(256) void rmsnorm_cast(
    const float* __restrict__ X, const float* __restrict__ gamma,
    short* __restrict__ Y, int C, int sx, int sy)
{
  const float* x = X + (size_t)blockIdx.x * sx;
  short* y = Y + (size_t)blockIdx.x * sy;
  const int tid = threadIdx.x;
  float ss = 0.f;
  for (int c = tid * 4; c < C; c += 1024) {
    float4 v = *(const float4*)(x + c);
    ss += v.x * v.x + v.y * v.y + v.z * v.z + v.w * v.w;
  }
  #pragma unroll
  for (int off = 32; off > 0; off >>= 1) ss += __shfl_down(ss, off, 64);
  __shared__ float red[4];
  if ((tid & 63) == 0) red[tid >> 6] = ss;
  __syncthreads();
  float tot = red[0] + red[1] + red[2] + red[3];
  float scale = rsqrtf(tot / (float)C + 1e-6f);
  for (int c = tid * 4; c < C; c += 1024) {
    float4 v = *(const float4*)(x + c);
    float4 g = *(const float4*)(gamma + c);
    short4 o = { f2bf(v.x * scale * g.x), f2bf(v.y * scale * g.y),
                 f2bf(v.z * scale * g.z), f2bf(v.w * scale * g.w) };
    *(short4*)(y + c) = o;
  }
}

// ---------------------------------------------------------------------------
// fused kv-branch: rmsnorm(kv[:,0:512]) -> ckv_b  AND  rope(kv[:,512:576]) -> kr
// ---------------------------------------------------------------------------
__global__ __launch_bounds__(256) void rmsnorm_kv_rope(
    const float* __restrict__ kvf, const float* __restrict__ gamma,
    const float* __restrict__ cosb, const float* __restrict__ sinb,
    short* __restrict__ ckv, short* __restrict__ kr)
{
  const int m = blockIdx.x;
  const float* x = kvf + (size_t)m * 640;
  short* y = ckv + (size_t)m * 512;
  const int tid = threadIdx.x;
  float ss = 0.f;
  for (int c = tid * 4; c < 512; c += 1024) {
    float4 v = *(const float4*)(x + c);
    ss += v.x * v.x + v.y * v.y + v.z * v.z + v.w * v.w;
  }
  #pragma unroll
  for (int off = 32; off > 0; off >>= 1) ss += __shfl_down(ss, off, 64);
  __shared__ float red[4];
  if ((tid & 63) == 0) red[tid >> 6] = ss;
  __syncthreads();
  float tot = red[0] + red[1] + red[2] + red[3];
  float scale = rsqrtf(tot / 512.f + 1e-6f);
  for (int c = tid * 4; c < 512; c += 1024) {
    float4 v = *(const float4*)(x + c);
    float4 g = *(const float4*)(gamma + c);
    short4 o = { f2bf(v.x * scale * g.x), f2bf(v.y * scale * g.y),
                 f2bf(v.z * scale * g.z), f2bf(v.w * scale * g.w) };
    *(short4*)(y + c) = o;
  }
  if (tid < 32) {
    const float* cb = cosb + (size_t)m * 64;
    const float* sb = sinb + (size_t)m * 64;
    float x1 = x[512 + tid], x2 = x[512 + tid + 32];
    kr[(size_t)m * 64 + tid]      = f2bf(x1 * cb[tid] - x2 * sb[tid]);
    kr[(size_t)m * 64 + tid + 32] = f2bf(x2 * cb[tid + 32] + x1 * sb[tid + 32]);
  }
}

// ---------------------------------------------------------------------------
// q (bf16 [m][3072]) -> rope + scale -> Qb (b,h,s,192) bf16
// ---------------------------------------------------------------------------
__global__ __launch_bounds__(256) void rope_pack_q(
    const short* __restrict__ q3, const float* __restrict__ cosb,
    const float* __restrict__ sinb, short* __restrict__ Qb)
{
  int m = blockIdx.x;
  int b = m >> 11, s = m & 2047;
  for (int i = threadIdx.x; i < 3072; i += 256) {
    int h = i / 192, c = i - h * 192;
    float v;
    if (c < 128) {
      v = bf2f(q3[(size_t)m * 3072 + i]);
    } else {
      int j = c - 128;
      float cs = cosb[(size_t)m * 64 + j], sn = sinb[(size_t)m * 64 + j];
      float xc = bf2f(q3[(size_t)m * 3072 + i]);
      if (j < 32) { float x2 = bf2f(q3[(size_t)m * 3072 + i + 32]); v = xc * cs - x2 * sn; }
      else        { float x1 = bf2f(q3[(size_t)m * 3072 + i - 32]); v = xc * cs + x1 * sn; }
    }
    Qb[(((size_t)(b * 16 + h)) * 2048 + s) * 192 + c] = f2bf(v * SCALE_F);
  }
}

// ---------------------------------------------------------------------------
// Kb (b,h,s,192) from kvx_b nope (bf16) + krope_b broadcast (bf16)
// ---------------------------------------------------------------------------
__global__ __launch_bounds__(256) void pack_k_b(
    const short* __restrict__ kvx, const short* __restrict__ kr, short* __restrict__ Kb)
{
  int m = blockIdx.x;
  int b = m >> 11, s = m & 2047;
  for (int i = threadIdx.x; i < 3072; i += 256) {
    int h = i / 192, c = i - h * 192;
    short v = (c < 128) ? kvx[((size_t)m * 16 + h) * 256 + c]
                        : kr[(size_t)m * 64 + (c - 128)];
    Kb[(((size_t)(b * 16 + h)) * 2048 + s) * 192 + c] = v;
  }
}

// V^T (b,h,128,2048) bf16 from kvx_b
__global__ __launch_bounds__(256) void pack_vt_b(
    const short* __restrict__ kvx, short* __restrict__ Vt)
{
  __shared__ short t[32][34];
  int s0 = blockIdx.x * 32, v0 = blockIdx.y * 32, bh = blockIdx.z;
  int b = bh >> 4, h = bh & 15;
  int c = threadIdx.x & 31, r4 = threadIdx.x >> 5;
  #pragma unroll
  for (int rr = 0; rr < 32; rr += 8) {
    int s = s0 + rr + r4;
    t[rr + r4][c] = kvx[(((size_t)(b * 2048 + s)) * 16 + h) * 256 + 128 + v0 + c];
  }
  __syncthreads();
  #pragma unroll
  for (int rr = 0; rr < 32; rr += 8) {
    int v = v0 + rr + r4;
    Vt[((size_t)bh * 128 + v) * 2048 + s0 + c] = t[c][rr + r4];
  }
}

// ---------------------------------------------------------------------------
// MFMA flash attention, v2: Q-tile 128 (4 waves x 32 rows), K-tile 64.
// Wave holds 2 register row-frags -> each LDS K/V frag feeds 2 MFMAs.
// qt reversed so heaviest causal blocks launch first.
// ---------------------------------------------------------------------------
#define KSTR 200
#define VSTR 72
#define PSTR 72

__global__ __launch_bounds__(256, 2) void flash_mfma(
    const short* __restrict__ Qb, const short* __restrict__ Kb,
    const short* __restrict__ Vt, short* __restrict__ attnb)
{
  __shared__ __align__(16) short Ks[64 * KSTR];      // 25.6 KB
  __shared__ __align__(16) short Vs[128 * VSTR];     // 18.4 KB
  __shared__ __align__(16) short Ps[4][32 * PSTR];   // 18.4 KB

  const int qt = (gridDim.x - 1) - blockIdx.x;       // heavy blocks first
  const int h = blockIdx.y, b = blockIdx.z;
  const int bh = b * 16 + h;
  const int tid = threadIdx.x;
  const int wave = tid >> 6, lane = tid & 63;
  const int quad = lane >> 4, n16 = lane & 15;
  const int qw = qt * 128 + wave * 32;               // wave's first q-row

  // Q A-frags: 2 row-groups x 6 k-slices, register resident
  bf16x8 aQ[2][6];
  #pragma unroll
  for (int rg = 0; rg < 2; ++rg) {
    const short* qp = Qb + ((size_t)bh * 2048 + qw + rg * 16 + n16) * 192 + quad * 8;
    #pragma unroll
    for (int t = 0; t < 6; ++t) aQ[rg][t] = *(const bf16x8*)(qp + t * 32);
  }

  f32x4 O[2][8];
  #pragma unroll
  for (int rg = 0; rg < 2; ++rg)
    #pragma unroll
    for (int i = 0; i < 8; ++i) O[rg][i] = (f32x4){0.f, 0.f, 0.f, 0.f};
  float m_i[2][4], l_i[2][4];
  #pragma unroll
  for (int rg = 0; rg < 2; ++rg)
    #pragma unroll
    for (int r = 0; r < 4; ++r) { m_i[rg][r] = NEG_BIG; l_i[rg][r] = 0.f; }

  short* pw = &Ps[wave][0];
  const int nkt = 2 * qt + 2;

  for (int kt = 0; kt < nkt; ++kt) {
    // ---- stage K (64x192) and V^T (128x64) ----
    {
      const short* src = Kb + ((size_t)bh * 2048 + kt * 64) * 192;
      for (int i = tid; i < 64 * 24; i += 256) {
        int r = i / 24, c = (i - r * 24) * 8;
        *(bf16x8*)&Ks[r * KSTR + c] = *(const bf16x8*)(src + r * 192 + c);
      }
      const short* vsrc = Vt + (size_t)bh * 128 * 2048 + kt * 64;
      for (int i = tid; i < 128 * 8; i += 256) {
        int v = i >> 3, c = (i & 7) * 8;
        *(bf16x8*)&Vs[v * VSTR + c] = *(const bf16x8*)(vsrc + (size_t)v * 2048 + c);
      }
    }
    __syncthreads();

    if (kt * 64 <= qw + 31) {      // wave has at least one unmasked key
      // ---- QK^T: 32x64 per wave ----
      float s[2][4][4];
      const bool tail = (kt * 64 + 63 > qw);
      #pragma unroll
      for (int ct = 0; ct < 4; ++ct) {
        if (kt * 64 + ct * 16 <= qw + 31) {
          f32x4 acc0 = (f32x4){0.f, 0.f, 0.f, 0.f};
          f32x4 acc1 = (f32x4){0.f, 0.f, 0.f, 0.f};
          const short* kp = &Ks[(ct * 16 + n16) * KSTR + quad * 8];
          #pragma unroll
          for (int t = 0; t < 6; ++t) {
            bf16x8 bk = *(const bf16x8*)(kp + t * 32);
            acc0 = __builtin_amdgcn_mfma_f32_16x16x32_bf16(aQ[0][t], bk, acc0, 0, 0, 0);
            acc1 = __builtin_amdgcn_mfma_f32_16x16x32_bf16(aQ[1][t], bk, acc1, 0, 0, 0);
          }
          #pragma unroll
          for (int r = 0; r < 4; ++r) { s[0][ct][r] = acc0[r]; s[1][ct][r] = acc1[r]; }
          if (tail) {
            int key = kt * 64 + ct * 16 + n16;
            #pragma unroll
            for (int rg = 0; rg < 2; ++rg)
              #pragma unroll
              for (int r = 0; r < 4; ++r)
                if (key > qw + rg * 16 + quad * 4 + r) s[rg][ct][r] = NEG_BIG;
          }
        } else {
          #pragma unroll
          for (int rg = 0; rg < 2; ++rg)
            #pragma unroll
            for (int r = 0; r < 4; ++r) s[rg][ct][r] = NEG_BIG;
        }
      }

      // ---- online softmax ----
      float alpha[2][4];
      #pragma unroll
      for (int rg = 0; rg < 2; ++rg)
        #pragma unroll
        for (int r = 0; r < 4; ++r) {
          float mx = fmaxf(fmaxf(s[rg][0][r], s[rg][1][r]), fmaxf(s[rg][2][r], s[rg][3][r]));
          mx = fmaxf(mx, __shfl_xor(mx, 1));
          mx = fmaxf(mx, __shfl_xor(mx, 2));
          mx = fmaxf(mx, __shfl_xor(mx, 4));
          mx = fmaxf(mx, __shfl_xor(mx, 8));
          float mnew = fmaxf(m_i[rg][r], mx);
          alpha[rg][r] = __expf(m_i[rg][r] - mnew);
          m_i[rg][r] = mnew;
          float rs = 0.f;
          #pragma unroll
          for (int ct = 0; ct < 4; ++ct) {
            float p = __expf(s[rg][ct][r] - mnew);
            s[rg][ct][r] = p;
            rs += p;
          }
          rs += __shfl_xor(rs, 1);
          rs += __shfl_xor(rs, 2);
          rs += __shfl_xor(rs, 4);
          rs += __shfl_xor(rs, 8);
          l_i[rg][r] = l_i[rg][r] * alpha[rg][r] + rs;
        }

      // rescale O + store P in A-layout LDS
      #pragma unroll
      for (int rg = 0; rg < 2; ++rg) {
        #pragma unroll
        for (int vt = 0; vt < 8; ++vt)
          #pragma unroll
          for (int r = 0; r < 4; ++r) O[rg][vt][r] *= alpha[rg][r];
        #pragma unroll
        for (int ct = 0; ct < 4; ++ct)
          #pragma unroll
          for (int r = 0; r < 4; ++r)
            pw[(rg * 16 + quad * 4 + r) * PSTR + ct * 16 + n16] = f2bf(s[rg][ct][r]);
      }

      // ---- PV: O[32x128] += P[32x64] @ V[64x128] ----
      #pragma unroll
      for (int ks = 0; ks < 2; ++ks) {
        if (kt * 64 + ks * 32 <= qw + 31) {
          bf16x8 aP0 = *(const bf16x8*)&pw[(n16) * PSTR + ks * 32 + quad * 8];
          bf16x8 aP1 = *(const bf16x8*)&pw[(16 + n16) * PSTR + ks * 32 + quad * 8];
          #pragma unroll
          for (int vt = 0; vt < 8; ++vt) {
            bf16x8 bV = *(const bf16x8*)&Vs[(vt * 16 + n16) * VSTR + ks * 32 + quad * 8];
            O[0][vt] = __builtin_amdgcn_mfma_f32_16x16x32_bf16(aP0, bV, O[0][vt], 0, 0, 0);
            O[1][vt] = __builtin_amdgcn_mfma_f32_16x16x32_bf16(aP1, bV, O[1][vt], 0, 0, 0);
          }
        }
      }
    }
    __syncthreads();
  }

  // ---- epilogue ----
  #pragma unroll
  for (int rg = 0; rg < 2; ++rg) {
    float inv_l[4];
    #pragma unroll
    for (int r = 0; r < 4; ++r) inv_l[r] = 1.f / l_i[rg][r];
    #pragma unroll
    for (int vt = 0; vt < 8; ++vt)
      #pragma unroll
      for (int r = 0; r < 4; ++r) {
        size_t m = (size_t)b * 2048 + qw + rg * 16 + quad * 4 + r;
        attnb[(m * 16 + h) * 128 + vt * 16 + n16] = f2bf(O[rg][vt][r] * inv_l[r]);
      }
  }
}

// ---------------------------------------------------------------------------
extern "C" void kernel_launch(void* const* d_in, const int* in_sizes, int n_in,
                              void* d_out, int out_size, void* d_ws, size_t ws_size,
                              hipStream_t stream)
{
  const float* hidden   = (const float*)d_in[0];
  const float* cosb     = (const float*)d_in[1];
  const float* sinb     = (const float*)d_in[2];
  const float* Wq_down  = (const float*)d_in[3];
  const float* q_gamma  = (const float*)d_in[4];
  const float* Wq_up    = (const float*)d_in[5];
  const float* Wkv_down = (const float*)d_in[6];
  const float* kv_gamma = (const float*)d_in[7];
  const float* Wkv_up   = (const float*)d_in[8];
  const float* Wo       = (const float*)d_in[9];
  float* out = (float*)d_out;

  // ---- workspace layout (identical aliasing to round 3, liveness verified) ----
  char* base = (char*)d_ws;
  short* hb  = (short*)base;                               // 4096x2048 bf16
  float* kvf = (float*)(base + 16777216);                  // 4096x640 fp32
  short* Qb  = (short*)base;                               // (b,h,s,192) bf16
  char* pB = base + 27262976;
  short* Wqd_b  = (short*)pB;                              // 1536x2048
  short* Wkvd_b = (short*)(pB + 6291456);                  // 640x2048 (padded)
  short* Wqu_b  = (short*)(pB + 8912896);                  // 3072x1536
  short* Wkvu_b = (short*)(pB + 18350080);                 // 4096x512
  short* Wo_b   = (short*)(pB + 22544384);                 // 2048x2048
  char* pC = pB + 30932992;
  float* q_lat = (float*)pC;                               // 4096x1536 fp32
  short* qb3   = (short*)pC;                               // 4096x3072 bf16
  short* Kb    = (short*)pC;                               // (b,h,s,192) bf16
  char* pD = pC + 25165824;
  short* q_lat_b = (short*)pD;                             // 4096x1536
  short* ckv_b   = (short*)(pD + 12582912);                // 4096x512
  short* krope_b = (short*)(pD + 16777216);                // 4096x64
  short* attn_b  = (short*)pD;                             // 4096x2048 bf16
  char* pE = pD + 17301504;
  short* kvx_b = (short*)pE;                               // 4096x4096 bf16
  char* pF = pE + 33554432;
  short* Vt = (short*)pF;                                  // (b,h,128,2048) bf16

  dim3 blk(256);

  // ---- casts (fused, 1 launch) ----
  cast_all<<<23296, blk, 0, stream>>>(hidden, Wq_down, Wq_up, Wkv_up, Wo, Wkv_down,
                                      hb, Wqd_b, Wqu_b, Wkvu_b, Wo_b, Wkvd_b);

  // ---- down-proj GEMMs (fp32 out) ----
  gemm_mfma<false><<<dim3(12, 32), blk, 0, stream>>>(hb, Wqd_b, q_lat, 1536, 2048);
  gemm_mfma<false><<<dim3(5, 32), blk, 0, stream>>>(hb, Wkvd_b, kvf, 640, 2048);

  // ---- norms + k-rope (kv branch fused) ----
  rmsnorm_cast<<<4096, blk, 0, stream>>>(q_lat, q_gamma, q_lat_b, 1536, 1536, 1536);
  rmsnorm_kv_rope<<<4096, blk, 0, stream>>>(kvf, kv_gamma, cosb, sinb, ckv_b, krope_b);

  // ---- up-proj GEMMs (bf16 out) ----
  gemm_mfma<true><<<dim3(24, 32), blk, 0, stream>>>(q_lat_b, Wqu_b, qb3, 3072, 1536);
  rope_pack_q<<<4096, blk, 0, stream>>>(qb3, cosb, sinb, Qb);
  gemm_mfma<true><<<dim3(32, 32), blk, 0, stream>>>(ckv_b, Wkvu_b, kvx_b, 4096, 512);
  pack_k_b<<<4096, blk, 0, stream>>>(kvx_b, krope_b, Kb);
  pack_vt_b<<<dim3(64, 4, 32), blk, 0, stream>>>(kvx_b, Vt);

  // ---- attention (bf16 out) + output proj ----
  flash_mfma<<<dim3(16, 16, 2), blk, 0, stream>>>(Qb, Kb, Vt, attn_b);
  gemm_mfma<false><<<dim3(16, 32), blk, 0, stream>>>(attn_b, Wo_b, out, 2048, 2048);
}

// Round 5
// 585.208 us; speedup vs baseline: 8.1573x; 1.1169x over previous
//
#include <hip/hip_runtime.h>
#include <math.h>

#define SCALE_F 0.0721687836487032f  // 192^-0.5
#define NEG_BIG -3.0e38f

typedef __attribute__((ext_vector_type(8))) short bf16x8;
typedef __attribute__((ext_vector_type(4))) float f32x4;

static __device__ __forceinline__ short f2bf(float f) {
  unsigned u = __float_as_uint(f);
  u += 0x7fffu + ((u >> 16) & 1u);   // RNE
  return (short)(u >> 16);
}

// async global->LDS, 16B per lane (m97-verified path)
static __device__ __forceinline__ void gl_lds16(const void* g, void* l) {
  __builtin_amdgcn_global_load_lds((const __attribute__((address_space(1))) void*)g,
                                   (__attribute__((address_space(3))) void*)l, 16, 0, 0);
}

// ---------------------------------------------------------------------------
// bf16 MFMA GEMM (m97 structure): C[M,N] = A[M,K] @ W[N,K]^T
// MODE 0: fp32 out row-major [M][N]
// MODE 2: q_up fused rope+scale+pack -> Qb (b,h,s,192) bf16   (N=3072)
// MODE 3: kv_up fused split -> Kb (b,h,s,192) nope cols + Vt (b,h,128,2048)
// ---------------------------------------------------------------------------
template <int MODE>
__global__ __launch_bounds__(256) void gemm_mfma(
    const short* __restrict__ A, const short* __restrict__ W,
    void* __restrict__ Cout, int N, int K,
    const float* __restrict__ cosb, const float* __restrict__ sinb,
    short* __restrict__ out2)
{
  __shared__ __align__(16) short As[128 * 32];
  __shared__ __align__(16) short Ws[128 * 32];
  const int tid = threadIdx.x;
  const int lane = tid & 63;
  const int quad = lane >> 4, n16 = lane & 15;
  const int bm = blockIdx.y * 128, bn = blockIdx.x * 128;
  const int wr = ((tid >> 6) >> 1) * 64, wc = ((tid >> 6) & 1) * 64;

  f32x4 acc[4][4];
  #pragma unroll
  for (int i = 0; i < 4; ++i)
    #pragma unroll
    for (int j = 0; j < 4; ++j) acc[i][j] = (f32x4){0.f, 0.f, 0.f, 0.f};

  const int r0 = tid >> 2, c0 = (tid & 3) * 8;
  const short* a0p = A + (size_t)(bm + r0) * K + c0;
  const short* a1p = A + (size_t)(bm + 64 + r0) * K + c0;
  const short* w0p = W + (size_t)(bn + r0) * K + c0;
  const short* w1p = W + (size_t)(bn + 64 + r0) * K + c0;
  short* asd0 = &As[tid * 8];
  short* asd1 = &As[2048 + tid * 8];
  short* wsd0 = &Ws[tid * 8];
  short* wsd1 = &Ws[2048 + tid * 8];

  for (int k0 = 0; k0 < K; k0 += 32) {
    gl_lds16(a0p, asd0);
    gl_lds16(a1p, asd1);
    gl_lds16(w0p, wsd0);
    gl_lds16(w1p, wsd1);
    a0p += 32; a1p += 32; w0p += 32; w1p += 32;
    __syncthreads();

    bf16x8 af[4], wf[4];
    #pragma unroll
    for (int i = 0; i < 4; ++i) {
      af[i] = *(const bf16x8*)&As[(wr + i * 16 + n16) * 32 + quad * 8];
      wf[i] = *(const bf16x8*)&Ws[(wc + i * 16 + n16) * 32 + quad * 8];
    }
    #pragma unroll
    for (int i = 0; i < 4; ++i)
      #pragma unroll
      for (int j = 0; j < 4; ++j)
        acc[i][j] = __builtin_amdgcn_mfma_f32_16x16x32_bf16(af[i], wf[j], acc[i][j], 0, 0, 0);
    __syncthreads();
  }

  if (MODE == 0) {
    #pragma unroll
    for (int i = 0; i < 4; ++i)
      #pragma unroll
      for (int r = 0; r < 4; ++r) {
        size_t row = (size_t)(bm + wr + i * 16 + quad * 4 + r);
        #pragma unroll
        for (int j = 0; j < 4; ++j)
          ((float*)Cout)[row * N + bn + wc + j * 16 + n16] = acc[i][j][r];
      }
  } else if (MODE == 2) {
    // q_up: rope last 64 of each 192-head, scale, pack to (b,h,s,192)
    #pragma unroll
    for (int i = 0; i < 4; ++i)
      #pragma unroll
      for (int r = 0; r < 4; ++r) {
        int m = bm + wr + i * 16 + quad * 4 + r;
        int bb = m >> 11, s = m & 2047;
        #pragma unroll
        for (int j = 0; j < 4; ++j) {
          int col = bn + wc + j * 16 + n16;
          int h = col / 192, c = col - h * 192;
          float v = acc[i][j][r];
          if (c >= 128) {
            int jr = c - 128;
            float part = acc[i][j ^ 2][r];   // partner col = col +/- 32 (proved in-wave)
            float cs = cosb[(size_t)m * 64 + jr], sn = sinb[(size_t)m * 64 + jr];
            v = (jr < 32) ? (v * cs - part * sn) : (v * cs + part * sn);
          }
          ((short*)Cout)[(((size_t)(bb * 16 + h)) * 2048 + s) * 192 + c] = f2bf(v * SCALE_F);
        }
      }
  } else {
    // kv_up: N=4096, head = col>>8; c<128 -> Kb nope, c>=128 -> Vt transposed
    #pragma unroll
    for (int i = 0; i < 4; ++i)
      #pragma unroll
      for (int r = 0; r < 4; ++r) {
        int m = bm + wr + i * 16 + quad * 4 + r;
        int bb = m >> 11, s = m & 2047;
        #pragma unroll
        for (int j = 0; j < 4; ++j) {
          int col = bn + wc + j * 16 + n16;
          int h = col >> 8, c = col & 255;
          short v = f2bf(acc[i][j][r]);
          if (c < 128)
            ((short*)Cout)[(((size_t)(bb * 16 + h)) * 2048 + s) * 192 + c] = v;
          else
            out2[((size_t)(bb * 16 + h) * 128 + (c - 128)) * 2048 + s] = v;
        }
      }
  }
}

// ---------------------------------------------------------------------------
// fused fp32 -> bf16 cast of hidden + all 5 weights (one launch)
// ---------------------------------------------------------------------------
__global__ __launch_bounds__(256) void cast_all(
    const float* __restrict__ hidden, const float* __restrict__ Wqd,
    const float* __restrict__ Wqu, const float* __restrict__ Wkvu,
    const float* __restrict__ Wo, const float* __restrict__ Wkvd,
    short* __restrict__ hb, short* __restrict__ Wqd_b, short* __restrict__ Wqu_b,
    short* __restrict__ Wkvu_b, short* __restrict__ Wo_b, short* __restrict__ Wkvd_b)
{
  int blk = blockIdx.x;
  const float* src; short* dst; int i;
  if (blk < 8192)       { src = hidden; dst = hb;     i = (blk * 256 + threadIdx.x) * 4; }
  else if (blk < 11264) { src = Wqd;  dst = Wqd_b;  i = ((blk - 8192) * 256 + threadIdx.x) * 4; }
  else if (blk < 15872) { src = Wqu;  dst = Wqu_b;  i = ((blk - 11264) * 256 + threadIdx.x) * 4; }
  else if (blk < 17920) { src = Wkvu; dst = Wkvu_b; i = ((blk - 15872) * 256 + threadIdx.x) * 4; }
  else if (blk < 22016) { src = Wo;   dst = Wo_b;   i = ((blk - 17920) * 256 + threadIdx.x) * 4; }
  else {
    i = ((blk - 22016) * 256 + threadIdx.x) * 4;
    int r = i >> 11;
    short4 o = {0, 0, 0, 0};
    if (r < 576) {
      float4 v = *(const float4*)(Wkvd + i);
      o.x = f2bf(v.x); o.y = f2bf(v.y); o.z = f2bf(v.z); o.w = f2bf(v.w);
    }
    *(short4*)(Wkvd_b + i) = o;
    return;
  }
  float4 v = *(const float4*)(src + i);
  short4 o = { f2bf(v.x), f2bf(v.y), f2bf(v.z), f2bf(v.w) };
  *(short4*)(dst + i) = o;
}

// ---------------------------------------------------------------------------
__global__ __launch_bounds__(256) void rmsnorm_cast(
    const float* __restrict__ X, const float* __restrict__ gamma,
    short* __restrict__ Y, int C, int sx, int sy)
{
  const float* x = X + (size_t)blockIdx.x * sx;
  short* y = Y + (size_t)blockIdx.x * sy;
  const int tid = threadIdx.x;
  float ss = 0.f;
  for (int c = tid * 4; c < C; c += 1024) {
    float4 v = *(const float4*)(x + c);
    ss += v.x * v.x + v.y * v.y + v.z * v.z + v.w * v.w;
  }
  #pragma unroll
  for (int off = 32; off > 0; off >>= 1) ss += __shfl_down(ss, off, 64);
  __shared__ float red[4];
  if ((tid & 63) == 0) red[tid >> 6] = ss;
  __syncthreads();
  float tot = red[0] + red[1] + red[2] + red[3];
  float scale = rsqrtf(tot / (float)C + 1e-6f);
  for (int c = tid * 4; c < C; c += 1024) {
    float4 v = *(const float4*)(x + c);
    float4 g = *(const float4*)(gamma + c);
    short4 o = { f2bf(v.x * scale * g.x), f2bf(v.y * scale * g.y),
                 f2bf(v.z * scale * g.z), f2bf(v.w * scale * g.w) };
    *(short4*)(y + c) = o;
  }
}

// ---------------------------------------------------------------------------
__global__ __launch_bounds__(256) void rmsnorm_kv_rope(
    const float* __restrict__ kvf, const float* __restrict__ gamma,
    const float* __restrict__ cosb, const float* __restrict__ sinb,
    short* __restrict__ ckv, short* __restrict__ kr)
{
  const int m = blockIdx.x;
  const float* x = kvf + (size_t)m * 640;
  short* y = ckv + (size_t)m * 512;
  const int tid = threadIdx.x;
  float ss = 0.f;
  for (int c = tid * 4; c < 512; c += 1024) {
    float4 v = *(const float4*)(x + c);
    ss += v.x * v.x + v.y * v.y + v.z * v.z + v.w * v.w;
  }
  #pragma unroll
  for (int off = 32; off > 0; off >>= 1) ss += __shfl_down(ss, off, 64);
  __shared__ float red[4];
  if ((tid & 63) == 0) red[tid >> 6] = ss;
  __syncthreads();
  float tot = red[0] + red[1] + red[2] + red[3];
  float scale = rsqrtf(tot / 512.f + 1e-6f);
  for (int c = tid * 4; c < 512; c += 1024) {
    float4 v = *(const float4*)(x + c);
    float4 g = *(const float4*)(gamma + c);
    short4 o = { f2bf(v.x * scale * g.x), f2bf(v.y * scale * g.y),
                 f2bf(v.z * scale * g.z), f2bf(v.w * scale * g.w) };
    *(short4*)(y + c) = o;
  }
  if (tid < 32) {
    const float* cb = cosb + (size_t)m * 64;
    const float* sb = sinb + (size_t)m * 64;
    float x1 = x[512 + tid], x2 = x[512 + tid + 32];
    kr[(size_t)m * 64 + tid]      = f2bf(x1 * cb[tid] - x2 * sb[tid]);
    kr[(size_t)m * 64 + tid + 32] = f2bf(x2 * cb[tid + 32] + x1 * sb[tid + 32]);
  }
}

// ---------------------------------------------------------------------------
// broadcast roped k_rope (bf16 [m][64]) into Kb cols 128..191 for all heads
// ---------------------------------------------------------------------------
__global__ __launch_bounds__(256) void krope_fill(
    const short* __restrict__ kr, short* __restrict__ Kb)
{
  int m = blockIdx.x;
  int b = m >> 11, s = m & 2047;
  for (int idx = threadIdx.x; idx < 1024; idx += 256) {
    int h = idx >> 6, j = idx & 63;
    Kb[(((size_t)(b * 16 + h)) * 2048 + s) * 192 + 128 + j] = kr[(size_t)m * 64 + j];
  }
}

// ---------------------------------------------------------------------------
// MFMA flash attention v3: frag-ordered LDS + global_load_lds DMA staging.
// Q-tile 128 (4 waves x 32 rows), K-tile 64.
// KsF chunk (ct,t) = 1KB holding K-frag for all 64 lanes; VsF chunk (ks,vt).
// ---------------------------------------------------------------------------
#define PSTR 72

__global__ __launch_bounds__(256, 2) void flash_mfma(
    const short* __restrict__ Qb, const short* __restrict__ Kb,
    const short* __restrict__ Vt, short* __restrict__ attnb)
{
  __shared__ __align__(16) short KsF[24 * 512];     // 24.6 KB, frag order
  __shared__ __align__(16) short VsF[16 * 512];     // 16.4 KB, frag order
  __shared__ __align__(16) short Ps[4][32 * PSTR];  // 18.4 KB

  const int qt = (gridDim.x - 1) - blockIdx.x;      // heavy blocks first
  const int h = blockIdx.y, b = blockIdx.z;
  const int bh = b * 16 + h;
  const int tid = threadIdx.x;
  const int wave = tid >> 6, lane = tid & 63;
  const int quad = lane >> 4, n16 = lane & 15;
  const int lq = lane >> 2, lr = lane & 3;          // staging: row-in-16, 16B chunk
  const int qw = qt * 128 + wave * 32;

  // Q A-frags: 2 row-groups x 6 k-slices, register resident
  bf16x8 aQ[2][6];
  #pragma unroll
  for (int rg = 0; rg < 2; ++rg) {
    const short* qp = Qb + ((size_t)bh * 2048 + qw + rg * 16 + n16) * 192 + quad * 8;
    #pragma unroll
    for (int t = 0; t < 6; ++t) aQ[rg][t] = *(const bf16x8*)(qp + t * 32);
  }

  f32x4 O[2][8];
  #pragma unroll
  for (int rg = 0; rg < 2; ++rg)
    #pragma unroll
    for (int i = 0; i < 8; ++i) O[rg][i] = (f32x4){0.f, 0.f, 0.f, 0.f};
  float m_i[2][4], l_i[2][4];
  #pragma unroll
  for (int rg = 0; rg < 2; ++rg)
    #pragma unroll
    for (int r = 0; r < 4; ++r) { m_i[rg][r] = NEG_BIG; l_i[rg][r] = 0.f; }

  short* pw = &Ps[wave][0];
  const int nkt = 2 * qt + 2;

  for (int kt = 0; kt < nkt; ++kt) {
    // ---- DMA staging: K chunks (ct=wave, t=u), V chunks (wave*4+u) ----
    {
      const short* kbase = Kb + ((size_t)bh * 2048 + kt * 64 + wave * 16 + lq) * 192 + lr * 8;
      #pragma unroll
      for (int u = 0; u < 6; ++u)
        gl_lds16(kbase + u * 32, &KsF[(wave * 6 + u) * 512 + lane * 8]);
      #pragma unroll
      for (int u = 0; u < 4; ++u) {
        int ci = wave * 4 + u, ks = ci >> 3, vt = ci & 7;
        const short* vbase = Vt + ((size_t)bh * 128 + vt * 16 + lq) * 2048 + kt * 64 + ks * 32 + lr * 8;
        gl_lds16(vbase, &VsF[ci * 512 + lane * 8]);
      }
    }
    __syncthreads();

    if (kt * 64 <= qw + 31) {
      // ---- QK^T: 32x64 per wave ----
      float s[2][4][4];
      const bool tail = (kt * 64 + 63 > qw);
      #pragma unroll
      for (int ct = 0; ct < 4; ++ct) {
        if (kt * 64 + ct * 16 <= qw + 31) {
          f32x4 acc0 = (f32x4){0.f, 0.f, 0.f, 0.f};
          f32x4 acc1 = (f32x4){0.f, 0.f, 0.f, 0.f};
          #pragma unroll
          for (int t = 0; t < 6; ++t) {
            bf16x8 bk = *(const bf16x8*)&KsF[(ct * 6 + t) * 512 + n16 * 32 + quad * 8];
            acc0 = __builtin_amdgcn_mfma_f32_16x16x32_bf16(aQ[0][t], bk, acc0, 0, 0, 0);
            acc1 = __builtin_amdgcn_mfma_f32_16x16x32_bf16(aQ[1][t], bk, acc1, 0, 0, 0);
          }
          #pragma unroll
          for (int r = 0; r < 4; ++r) { s[0][ct][r] = acc0[r]; s[1][ct][r] = acc1[r]; }
          if (tail) {
            int key = kt * 64 + ct * 16 + n16;
            #pragma unroll
            for (int rg = 0; rg < 2; ++rg)
              #pragma unroll
              for (int r = 0; r < 4; ++r)
                if (key > qw + rg * 16 + quad * 4 + r) s[rg][ct][r] = NEG_BIG;
          }
        } else {
          #pragma unroll
          for (int rg = 0; rg < 2; ++rg)
            #pragma unroll
            for (int r = 0; r < 4; ++r) s[rg][ct][r] = NEG_BIG;
        }
      }

      // ---- online softmax ----
      float alpha[2][4];
      #pragma unroll
      for (int rg = 0; rg < 2; ++rg)
        #pragma unroll
        for (int r = 0; r < 4; ++r) {
          float mx = fmaxf(fmaxf(s[rg][0][r], s[rg][1][r]), fmaxf(s[rg][2][r], s[rg][3][r]));
          mx = fmaxf(mx, __shfl_xor(mx, 1));
          mx = fmaxf(mx, __shfl_xor(mx, 2));
          mx = fmaxf(mx, __shfl_xor(mx, 4));
          mx = fmaxf(mx, __shfl_xor(mx, 8));
          float mnew = fmaxf(m_i[rg][r], mx);
          alpha[rg][r] = __expf(m_i[rg][r] - mnew);
          m_i[rg][r] = mnew;
          float rs = 0.f;
          #pragma unroll
          for (int ct = 0; ct < 4; ++ct) {
            float p = __expf(s[rg][ct][r] - mnew);
            s[rg][ct][r] = p;
            rs += p;
          }
          rs += __shfl_xor(rs, 1);
          rs += __shfl_xor(rs, 2);
          rs += __shfl_xor(rs, 4);
          rs += __shfl_xor(rs, 8);
          l_i[rg][r] = l_i[rg][r] * alpha[rg][r] + rs;
        }

      // rescale O + store P in A-layout LDS
      #pragma unroll
      for (int rg = 0; rg < 2; ++rg) {
        #pragma unroll
        for (int vt = 0; vt < 8; ++vt)
          #pragma unroll
          for (int r = 0; r < 4; ++r) O[rg][vt][r] *= alpha[rg][r];
        #pragma unroll
        for (int ct = 0; ct < 4; ++ct)
          #pragma unroll
          for (int r = 0; r < 4; ++r)
            pw[(rg * 16 + quad * 4 + r) * PSTR + ct * 16 + n16] = f2bf(s[rg][ct][r]);
      }

      // ---- PV: O[32x128] += P[32x64] @ V[64x128] ----
      #pragma unroll
      for (int ks = 0; ks < 2; ++ks) {
        if (kt * 64 + ks * 32 <= qw + 31) {
          bf16x8 aP0 = *(const bf16x8*)&pw[(n16) * PSTR + ks * 32 + quad * 8];
          bf16x8 aP1 = *(const bf16x8*)&pw[(16 + n16) * PSTR + ks * 32 + quad * 8];
          #pragma unroll
          for (int vt = 0; vt < 8; ++vt) {
            bf16x8 bV = *(const bf16x8*)&VsF[(ks * 8 + vt) * 512 + n16 * 32 + quad * 8];
            O[0][vt] = __builtin_amdgcn_mfma_f32_16x16x32_bf16(aP0, bV, O[0][vt], 0, 0, 0);
            O[1][vt] = __builtin_amdgcn_mfma_f32_16x16x32_bf16(aP1, bV, O[1][vt], 0, 0, 0);
          }
        }
      }
    }
    __syncthreads();
  }

  // ---- epilogue ----
  #pragma unroll
  for (int rg = 0; rg < 2; ++rg) {
    float inv_l[4];
    #pragma unroll
    for (int r = 0; r < 4; ++r) inv_l[r] = 1.f / l_i[rg][r];
    #pragma unroll
    for (int vt = 0; vt < 8; ++vt)
      #pragma unroll
      for (int r = 0; r < 4; ++r) {
        size_t m = (size_t)b * 2048 + qw + rg * 16 + quad * 4 + r;
        attnb[(m * 16 + h) * 128 + vt * 16 + n16] = f2bf(O[rg][vt][r] * inv_l[r]);
      }
  }
}

// ---------------------------------------------------------------------------
extern "C" void kernel_launch(void* const* d_in, const int* in_sizes, int n_in,
                              void* d_out, int out_size, void* d_ws, size_t ws_size,
                              hipStream_t stream)
{
  const float* hidden   = (const float*)d_in[0];
  const float* cosb     = (const float*)d_in[1];
  const float* sinb     = (const float*)d_in[2];
  const float* Wq_down  = (const float*)d_in[3];
  const float* q_gamma  = (const float*)d_in[4];
  const float* Wq_up    = (const float*)d_in[5];
  const float* Wkv_down = (const float*)d_in[6];
  const float* kv_gamma = (const float*)d_in[7];
  const float* Wkv_up   = (const float*)d_in[8];
  const float* Wo       = (const float*)d_in[9];
  float* out = (float*)d_out;

  // ---- workspace (117 MB, aliased; liveness verified) ----
  char* base = (char*)d_ws;
  // region A: hb (16.78M) + kvf (10.49M) -> Qb (25.17M) after both dead
  short* hb  = (short*)base;
  float* kvf = (float*)(base + 16777216);
  short* Qb  = (short*)base;
  char* pB = base + 27262976;                  // weights, 30.93M
  short* Wqd_b  = (short*)pB;
  short* Wkvd_b = (short*)(pB + 6291456);
  short* Wqu_b  = (short*)(pB + 8912896);
  short* Wkvu_b = (short*)(pB + 18350080);
  short* Wo_b   = (short*)(pB + 22544384);
  char* pC = pB + 30932992;                    // q_lat f32 (25.17M) -> Kb (25.17M)
  float* q_lat = (float*)pC;
  short* Kb    = (short*)pC;
  char* pD = pC + 25165824;                    // q_lat_b + ckv_b + krope_b -> attn_b
  short* q_lat_b = (short*)pD;                 // 12.58M
  short* ckv_b   = (short*)(pD + 12582912);    // 4.19M
  short* krope_b = (short*)(pD + 16777216);    // 0.52M (beyond attn_b end)
  short* attn_b  = (short*)pD;                 // 16.78M
  char* pE = pD + 17301504;
  short* Vt = (short*)pE;                      // 16.78M

  dim3 blk(256);

  // ---- casts (1 launch) ----
  cast_all<<<23296, blk, 0, stream>>>(hidden, Wq_down, Wq_up, Wkv_up, Wo, Wkv_down,
                                      hb, Wqd_b, Wqu_b, Wkvu_b, Wo_b, Wkvd_b);

  // ---- down-proj GEMMs (fp32 out) ----
  gemm_mfma<0><<<dim3(12, 32), blk, 0, stream>>>(hb, Wqd_b, q_lat, 1536, 2048, nullptr, nullptr, nullptr);
  gemm_mfma<0><<<dim3(5, 32), blk, 0, stream>>>(hb, Wkvd_b, kvf, 640, 2048, nullptr, nullptr, nullptr);

  // ---- norms + k-rope ----
  rmsnorm_cast<<<4096, blk, 0, stream>>>(q_lat, q_gamma, q_lat_b, 1536, 1536, 1536);
  rmsnorm_kv_rope<<<4096, blk, 0, stream>>>(kvf, kv_gamma, cosb, sinb, ckv_b, krope_b);

  // ---- up-proj GEMMs, fused epilogues ----
  gemm_mfma<2><<<dim3(24, 32), blk, 0, stream>>>(q_lat_b, Wqu_b, Qb, 3072, 1536, cosb, sinb, nullptr);
  gemm_mfma<3><<<dim3(32, 32), blk, 0, stream>>>(ckv_b, Wkvu_b, Kb, 4096, 512, nullptr, nullptr, Vt);
  krope_fill<<<4096, blk, 0, stream>>>(krope_b, Kb);

  // ---- attention + output proj ----
  flash_mfma<<<dim3(16, 16, 2), blk, 0, stream>>>(Qb, Kb, Vt, attn_b);
  gemm_mfma<0><<<dim3(16, 32), blk, 0, stream>>>(attn_b, Wo_b, out, 2048, 2048, nullptr, nullptr, nullptr);
}